// Round 1
// baseline (650.566 us; speedup 1.0000x reference)
//
#include <hip/hip_runtime.h>
#include <hip/hip_bf16.h>

#define B_   128
#define TE_  512
#define TD_  128
#define EH_  512
#define DH_  512
#define KC_  7
#define CC_  105
#define G_   2048   // 4*DH
#define KX_  617    // EH + CC
#define KP_  640    // padded K for gates GEMM
#define GNT  10     // KP_/64 K-tiles for gates GEMM

typedef __attribute__((ext_vector_type(8))) short bf16x8;
typedef __attribute__((ext_vector_type(4))) float f32x4;

__device__ __forceinline__ float sigm(float x){ return 1.f/(1.f + __expf(-x)); }
__device__ __forceinline__ float tanhf_fast(float x){
  float e = __expf(2.f*x);
  return 1.f - 2.f/(e + 1.f);
}

// fp32 -> bf16 (RNE)
__device__ __forceinline__ unsigned short f2bf(float f){
  unsigned int u = __float_as_uint(f);
  unsigned int r = (u + 0x7fffu + ((u >> 16) & 1u)) >> 16;
  return (unsigned short)r;
}

__device__ __forceinline__ float dot512f(const float* a, const float* b) {
  const float4* a4 = (const float4*)a; const float4* b4 = (const float4*)b;
  float acc = 0.f;
  #pragma unroll 8
  for (int q = 0; q < 128; ++q) {
    float4 x = a4[q], y = b4[q];
    acc += x.x*y.x + x.y*y.y + x.z*y.z + x.w*y.w;
  }
  return acc;
}

// async global->LDS, 16B per lane; LDS dest = wave-uniform base + lane*16
typedef __attribute__((address_space(3))) unsigned int lds_u32_t;
typedef __attribute__((address_space(1))) const unsigned int glb_u32_t;
__device__ __forceinline__ void gload16(const void* g, void* l) {
  __builtin_amdgcn_global_load_lds((glb_u32_t*)g, (lds_u32_t*)l, 16, 0, 0);
}

// ---------------- workspace layout (bytes) ----------------
static const size_t OFF_PHI  = 0;                                         // 1 MB
static const size_t OFF_WA   = OFF_PHI  + (size_t)TE_*EH_*4;              // 64 KB
static const size_t OFF_HPRE = OFF_WA   + (size_t)B_*TD_*4;               // 1 MB
static const size_t OFF_EP   = OFF_HPRE + (size_t)B_*G_*4;                // 4 KB
static const size_t OFF_CP   = OFF_EP   + 4096;                           // 53.8 KB
static const size_t OFF_ET   = ((OFF_CP + (size_t)B_*CC_*4 + 255)/256)*256; // 33.5 MB fp32 [b][t][i]; X bf16 aliases
static const size_t OFF_STAT = OFF_ET + (size_t)B_*TE_*TD_*4;             // 128 KB
static const size_t OFF_P    = ((OFF_STAT + (size_t)2*B_*TD_*4 + 255)/256)*256; // 16.7 MB bf16
static const size_t OFF_LT   = OFF_P  + (size_t)B_*TD_*TE_*2;             // 67 MB bf16
static const size_t OFF_WR   = OFF_LT + (size_t)B_*TE_*EH_*2;             // 2.6 MB bf16
// scratch aliases inside P region (P written later by k_trP):
static const size_t OFF_PT   = OFF_P;                                     // 1 MB fp32 phi_w^T
static const size_t OFF_SUM  = OFF_PT + (size_t)TE_*EH_*4;                // 16 KB scan sums
static const size_t OFF_UB   = OFF_P + (size_t)1536*1024;                 // 512 KB Ua_w bf16 (dead before k_trP)

// ---- phi_w [e][t] -> phiT [t][e] ----
__global__ __launch_bounds__(256) void k_trw(const float* __restrict__ phi_w,
                                             float* __restrict__ phiT) {
  int e0 = blockIdx.x * 64, t0 = blockIdx.y * 64;
  __shared__ float tile[64][65];
  int tid = threadIdx.x;
  int r = tid >> 2, c16 = (tid & 3) * 16;
  const float4* src = (const float4*)(phi_w + (size_t)(e0 + r)*TE_ + t0 + c16);
  float4 v0 = src[0], v1 = src[1], v2 = src[2], v3 = src[3];
  *(float4*)&tile[r][c16]    = v0;
  *(float4*)&tile[r][c16+4]  = v1;
  *(float4*)&tile[r][c16+8]  = v2;
  *(float4*)&tile[r][c16+12] = v3;
  __syncthreads();
  float o[16];
  #pragma unroll
  for (int j = 0; j < 16; ++j) o[j] = tile[c16+j][r];
  float* dst = phiT + (size_t)(t0 + r)*EH_ + e0 + c16;
  *(float4*)dst      = *(float4*)&o[0];
  *(float4*)(dst+4)  = *(float4*)&o[4];
  *(float4*)(dst+8)  = *(float4*)&o[8];
  *(float4*)(dst+12) = *(float4*)&o[12];
}

// ---- split exclusive scan over t ----
__global__ void k_phiA(const float* __restrict__ phiT, float* __restrict__ phi,
                       float* __restrict__ sums) {
  int e = blockIdx.x * 256 + threadIdx.x;   // 512
  int z = blockIdx.y;                        // 8 chunks of 64 t
  float acc = 0.f;
  for (int t = z*64; t < z*64 + 64; ++t) {
    phi[(size_t)t*EH_ + e] = acc;
    acc += phiT[(size_t)t*EH_ + e];
  }
  sums[z*EH_ + e] = acc;
}
__global__ void k_phiB(const float* __restrict__ sums, const float* __restrict__ phi_b,
                       float* __restrict__ phi) {
  int e = blockIdx.x * 256 + threadIdx.x;
  int z = blockIdx.y;
  float off = phi_b[e];
  for (int zz = 0; zz < z; ++zz) off += sums[zz*EH_ + e];
  for (int t = z*64; t < z*64 + 64; ++t)
    phi[(size_t)t*EH_ + e] += off;
}

__global__ void k_wa(const float* __restrict__ s_i, const float* __restrict__ Wa_w,
                     const float* __restrict__ Wa_b, const float* __restrict__ va_w,
                     float* __restrict__ wa) {
  int id = blockIdx.x * blockDim.x + threadIdx.x;  // 16384
  int b = id >> 7, d = id & 127;
  float acc = Wa_b[d] + dot512f(s_i + (size_t)b*DH_, Wa_w + (size_t)d*DH_);
  wa[id] = tanhf_fast(acc) * va_w[d];
}

__global__ void k_hpre(const float* __restrict__ s_i, const float* __restrict__ Whh,
                       const float* __restrict__ bih, const float* __restrict__ bhh,
                       float* __restrict__ hpre) {
  int id = blockIdx.x * blockDim.x + threadIdx.x; // 262144
  int b = id >> 11, g = id & 2047;
  hpre[id] = bih[g] + bhh[g] + dot512f(s_i + (size_t)b*DH_, Whh + (size_t)g*DH_);
}

// ---- ep: one wave per (b,k) ----
__global__ __launch_bounds__(256) void k_ep(const float* __restrict__ CNNs,
                                            const float* __restrict__ wij_w,
                                            const float* __restrict__ wij_b,
                                            const float* __restrict__ s_i,
                                            float* __restrict__ ep) {
  int gw = blockIdx.x * 4 + (threadIdx.x >> 6);
  int lane = threadIdx.x & 63;
  if (gw >= B_*KC_) return;
  int b = gw / KC_, k = gw % KC_;
  const float* cr = CNNs + (size_t)(b*KC_ + k)*CC_;
  const float* wr = wij_w + (size_t)k*KX_;
  float acc = 0.f;
  for (int c = lane; c < CC_; c += 64) acc += cr[c] * wr[c];
  const float* sr = s_i + (size_t)b*DH_;
  const float* wsr = wr + CC_;
  #pragma unroll
  for (int j = 0; j < 8; ++j) { int h = lane + j*64; acc += sr[h] * wsr[h]; }
  #pragma unroll
  for (int m = 32; m; m >>= 1) acc += __shfl_xor(acc, m, 64);
  if (lane == 0) ep[gw] = tanhf_fast(acc + wij_b[k]);
}

__global__ void k_cnn_fin(const float* __restrict__ ep, const float* __restrict__ CNNs,
                          float* __restrict__ cp) {
  __shared__ float red[1024];
  __shared__ float apl[B_*KC_];
  int tid = threadIdx.x;
  red[tid] = (tid < B_*KC_) ? ep[tid] : 0.f;
  __syncthreads();
  for (int off = 512; off > 0; off >>= 1) {
    if (tid < off) red[tid] += red[tid + off];
    __syncthreads();
  }
  float S = red[0];
  if (tid < B_*KC_) apl[tid] = __expf(ep[tid]) / S;   // ref: exp(ep)/sum(ep), GLOBAL sum
  __syncthreads();
  for (int idx = tid; idx < B_*CC_; idx += blockDim.x) {
    int b = idx / CC_, c = idx % CC_;
    float acc = 0.f;
    #pragma unroll
    for (int k = 0; k < KC_; ++k)
      acc += apl[b*KC_ + k] * CNNs[(size_t)(b*KC_ + k)*CC_ + c];
    cp[idx] = acc;
  }
}

// ---- Wih fp32 -> bf16 [2048][640], rows reordered nr = dh*4+gate ----
__global__ void k_cvtW(const float* __restrict__ Wih, unsigned short* __restrict__ Wr) {
  int id = blockIdx.x * 256 + threadIdx.x;    // 2048*80
  int nr = id / 80, c8 = (id % 80) * 8;
  int gate = nr & 3, dh = nr >> 2;
  const float* src = Wih + (size_t)(gate*DH_ + dh)*KX_;
  unsigned short o[8];
  #pragma unroll
  for (int j = 0; j < 8; ++j) {
    int col = c8 + j;
    o[j] = (col < KX_) ? f2bf(src[col]) : 0;
  }
  *(uint4*)(Wr + (size_t)nr*KP_ + c8) = *(uint4*)o;
}

// ---- Ua_w fp32 -> bf16 (batch-invariant; converted ONCE instead of 128x in k_bandmm) ----
__global__ void k_cvtU(const float* __restrict__ Ua_w, unsigned short* __restrict__ Ub) {
  int id = blockIdx.x * 256 + threadIdx.x;    // 32768 threads * 8 elems
  const float4* s = (const float4*)Ua_w + (size_t)id*2;
  float4 a = s[0], b = s[1];
  unsigned short o[8] = {f2bf(a.x),f2bf(a.y),f2bf(a.z),f2bf(a.w),
                         f2bf(b.x),f2bf(b.y),f2bf(b.z),f2bf(b.w)};
  *(uint4*)(Ub + (size_t)id*8) = *(uint4*)o;
}

// ---- LSTM [b][t][e] fp32 -> LT [b][e][t] bf16 ----
__global__ __launch_bounds__(256) void k_ltrans(const float* __restrict__ LSTM,
                                                unsigned short* __restrict__ LT) {
  int e0 = blockIdx.x * 64, t0 = blockIdx.y * 64, b = blockIdx.z;
  __shared__ float tile[64][65];
  int tid = threadIdx.x;
  int tt = tid >> 2, c16 = (tid & 3) * 16;
  const float4* src = (const float4*)(LSTM + ((size_t)b*TE_ + t0 + tt)*EH_ + e0 + c16);
  float4 v0 = src[0], v1 = src[1], v2 = src[2], v3 = src[3];
  *(float4*)&tile[tt][c16]    = v0;
  *(float4*)&tile[tt][c16+4]  = v1;
  *(float4*)&tile[tt][c16+8]  = v2;
  *(float4*)&tile[tt][c16+12] = v3;
  __syncthreads();
  int e = tid >> 2, t16 = (tid & 3) * 16;
  unsigned short o[16];
  #pragma unroll
  for (int j = 0; j < 16; ++j) o[j] = f2bf(tile[t16+j][e]);
  unsigned short* dst = LT + ((size_t)b*EH_ + e0 + e)*TE_ + t0 + t16;
  *(uint4*)dst     = *(uint4*)&o[0];
  *(uint4*)(dst+8) = *(uint4*)&o[8];
}

// ---------- phase 1: banded logits MFMA band-GEMM ----------
#define BMM_M 64
#define LDA_  40
#define LDB_  40
__global__ __launch_bounds__(256) void k_bandmm(const float* __restrict__ LSTM,
                                                const float* __restrict__ phi,
                                                const unsigned short* __restrict__ Ub,
                                                const float* __restrict__ Ua_b,
                                                const float* __restrict__ va_w,
                                                const float* __restrict__ va_b,
                                                const float* __restrict__ wa,
                                                float* __restrict__ ET) {
  int t0 = blockIdx.x * BMM_M;   // 8 tiles
  int b  = blockIdx.y;           // 128
  int s_base = 321 - t0;
  __shared__ short sA[BMM_M * LDA_];
  __shared__ short sB[192 * LDB_];
  int tid = threadIdx.x;
  int wave = tid >> 6, lane = tid & 63;
  int quad = lane >> 4, l16 = lane & 15;

  f32x4 acc[4][3];
  #pragma unroll
  for (int m = 0; m < 4; ++m)
    #pragma unroll
    for (int n = 0; n < 3; ++n)
      acc[m][n] = (f32x4){0.f, 0.f, 0.f, 0.f};

  int arow = tid >> 2;             // 0..63
  int ach  = (tid & 3) * 8;        // shorts
  int aq   = ach >> 2;             // float4 units

  const float4* baseL = (const float4*)(LSTM + ((size_t)b*TE_ + t0 + arow)*EH_);
  const float4* baseP = (const float4*)(phi + (size_t)(t0 + arow)*EH_);
  const unsigned short* ubase[3];
  int brow[3], bch[3];
  #pragma unroll
  for (int c = 0; c < 3; ++c) {
    int idx = c*256 + tid;
    brow[c] = idx >> 2;
    bch[c]  = (idx & 3) * 8;
    int s = s_base + brow[c];
    int sc = s < 0 ? 0 : (s > 511 ? 511 : s);
    ubase[c] = Ub + (size_t)sc*EH_ + bch[c];
  }

  float4 l0 = baseL[aq], l1 = baseL[aq+1], p0 = baseP[aq], p1 = baseP[aq+1];
  uint4 ub0[3];
  #pragma unroll
  for (int c = 0; c < 3; ++c) ub0[c] = *(const uint4*)(ubase[c]);

  for (int k0 = 0; k0 < EH_; k0 += 32) {
    unsigned short at[8];
    at[0]=f2bf(l0.x*p0.x); at[1]=f2bf(l0.y*p0.y); at[2]=f2bf(l0.z*p0.z); at[3]=f2bf(l0.w*p0.w);
    at[4]=f2bf(l1.x*p1.x); at[5]=f2bf(l1.y*p1.y); at[6]=f2bf(l1.z*p1.z); at[7]=f2bf(l1.w*p1.w);
    uint4 ust[3];
    #pragma unroll
    for (int c = 0; c < 3; ++c) ust[c] = ub0[c];
    if (k0 + 32 < EH_) {                       // prefetch next chunk
      int q = (k0 + 32) >> 2;
      l0 = baseL[q+aq]; l1 = baseL[q+aq+1]; p0 = baseP[q+aq]; p1 = baseP[q+aq+1];
      #pragma unroll
      for (int c = 0; c < 3; ++c) ub0[c] = *(const uint4*)(ubase[c] + k0 + 32);
    }
    __syncthreads();
    *(uint4*)&sA[arow*LDA_ + ach] = *(uint4*)at;
    #pragma unroll
    for (int c = 0; c < 3; ++c)
      *(uint4*)&sB[brow[c]*LDB_ + bch[c]] = ust[c];
    __syncthreads();
    bf16x8 bfr[3];
    #pragma unroll
    for (int n = 0; n < 3; ++n)
      bfr[n] = *(const bf16x8*)&sB[(l16 + (wave*3 + n)*16)*LDB_ + quad*8];
    #pragma unroll
    for (int m = 0; m < 4; ++m) {
      bf16x8 af = *(const bf16x8*)&sA[(l16 + m*16)*LDA_ + quad*8];
      #pragma unroll
      for (int n = 0; n < 3; ++n)
        acc[m][n] = __builtin_amdgcn_mfma_f32_16x16x32_bf16(af, bfr[n], acc[m][n], 0, 0, 0);
    }
  }

  float vb = va_b[0];
  #pragma unroll
  for (int n = 0; n < 3; ++n) {
    int s = s_base + wave*48 + n*16 + l16;
    float ub = (s >= 0 && s < TE_) ? Ua_b[s] : 0.f;
    float vw = (s >= 0 && s < TE_) ? va_w[TD_ + s] : 0.f;
    #pragma unroll
    for (int m = 0; m < 4; ++m) {
      #pragma unroll
      for (int r = 0; r < 4; ++r) {
        int t = t0 + m*16 + quad*4 + r;
        int i = s + t - 384;
        if (i >= 0 && i < TD_) {
          float val;
          if (s >= 0) val = tanhf_fast(acc[m][n][r] + ub) * vw + vb;
          else        val = wa[b*TD_ + s + 128] + vb;
          ET[((size_t)b*TE_ + t)*TD_ + i] = val;
        }
      }
    }
  }
}

// ---------------- phase 2: softmax stats over t ----------------
__global__ __launch_bounds__(256) void k_stats(const float* __restrict__ ET,
                                               float* __restrict__ stat) {
  int i0 = blockIdx.x * 64, b = blockIdx.y;
  __shared__ float red[4][64], smax[64];
  int tid = threadIdx.x;
  int q = tid >> 6, il = tid & 63;
  const float* col = ET + (size_t)b*TE_*TD_ + i0 + il;
  float m = -1e30f;
  for (int t = q*128; t < q*128 + 128; ++t) m = fmaxf(m, col[(size_t)t*TD_]);
  red[q][il] = m;
  __syncthreads();
  if (tid < 64) {
    float mm = fmaxf(fmaxf(red[0][tid], red[1][tid]), fmaxf(red[2][tid], red[3][tid]));
    smax[tid] = mm;
  }
  __syncthreads();
  float mm = smax[il];
  float s = 0.f;
  for (int t = q*128; t < q*128 + 128; ++t) s += __expf(col[(size_t)t*TD_] - mm);
  __syncthreads();
  red[q][il] = s;
  __syncthreads();
  if (tid < 64) {
    float ss = red[0][tid] + red[1][tid] + red[2][tid] + red[3][tid];
    stat[b*TD_ + i0 + tid] = smax[tid];
    stat[(size_t)B_*TD_ + b*TD_ + i0 + tid] = 1.f/ss;
  }
}

// ---- ET [b][t][i] + stats -> P [b][i][t] bf16 (softmax applied, transposed) ----
__global__ __launch_bounds__(256) void k_trP(const float* __restrict__ ET,
                                             const float* __restrict__ stat,
                                             unsigned short* __restrict__ P) {
  int t0 = blockIdx.x * 64, i0 = blockIdx.y * 64, b = blockIdx.z;
  __shared__ float tile[64][65];
  __shared__ float smL[64], svL[64];
  int tid = threadIdx.x;
  if (tid < 64) {
    smL[tid] = stat[b*TD_ + i0 + tid];
    svL[tid] = stat[(size_t)B_*TD_ + b*TD_ + i0 + tid];
  }
  int tt = tid >> 2, c16 = (tid & 3) * 16;
  const float4* src = (const float4*)(ET + ((size_t)b*TE_ + t0 + tt)*TD_ + i0 + c16);
  float4 v[4]; v[0] = src[0]; v[1] = src[1]; v[2] = src[2]; v[3] = src[3];
  __syncthreads();
  const float* vf = (const float*)v;
  #pragma unroll
  for (int j = 0; j < 16; ++j)
    tile[tt][c16+j] = __expf(vf[j] - smL[c16+j]) * svL[c16+j];
  __syncthreads();
  int i = tid >> 2, t16 = (tid & 3) * 16;
  unsigned short o[16];
  #pragma unroll
  for (int j = 0; j < 16; ++j) o[j] = f2bf(tile[t16+j][i]);
  unsigned short* dst = P + ((size_t)b*TD_ + i0 + i)*TE_ + t0 + t16;
  *(uint4*)dst     = *(uint4*)&o[0];
  *(uint4*)(dst+8) = *(uint4*)&o[8];
}

// ---- fill X[:,512:640] from cp (bf16), zero pad ----
__global__ void k_cp_fill(const float* __restrict__ cp, unsigned short* __restrict__ X) {
  int id = blockIdx.x * 256 + threadIdx.x;  // 16384*16
  int m = id >> 4, c8 = (id & 15) * 8;
  int b = m >> 7;
  unsigned short o[8];
  #pragma unroll
  for (int j = 0; j < 8; ++j) {
    int c = c8 + j;
    o[j] = (c < CC_) ? f2bf(cp[b*CC_ + c]) : 0;
  }
  *(uint4*)(X + (size_t)m*KP_ + EH_ + c8) = *(uint4*)o;
}

// ------ phase 3 (MFMA, BK=32): X[b*128+i][e] = sum_t P[b][i][t]*LT[b][e][t] ------
#define CI_LD 40
__global__ __launch_bounds__(256) void k_ci_mm(const unsigned short* __restrict__ P,
                                               const unsigned short* __restrict__ LT,
                                               unsigned short* __restrict__ X) {
  int b = blockIdx.x, e0 = blockIdx.y * 128;
  __shared__ short sA[128 * CI_LD];
  __shared__ short sB[128 * CI_LD];
  int tid = threadIdx.x;
  int wave = tid >> 6, lane = tid & 63, quad = lane >> 4, l16 = lane & 15;
  int wm = wave >> 1, wn = wave & 1;
  int row = tid >> 1, ho = (tid & 1) * 16;

  const unsigned short* pa = P + ((size_t)b*TD_ + row)*TE_ + ho;
  const unsigned short* pb = LT + ((size_t)b*EH_ + e0 + row)*TE_ + ho;

  f32x4 acc[4][4];
  #pragma unroll
  for (int m = 0; m < 4; ++m)
    #pragma unroll
    for (int n = 0; n < 4; ++n)
      acc[m][n] = (f32x4){0.f, 0.f, 0.f, 0.f};

  uint4 a0 = *(const uint4*)pa, a1 = *(const uint4*)(pa + 8);
  uint4 b0 = *(const uint4*)pb, b1 = *(const uint4*)(pb + 8);

  for (int k0 = 0; k0 < TE_; k0 += 32) {
    uint4 na0, na1, nb0, nb1;
    if (k0 + 32 < TE_) {
      na0 = *(const uint4*)(pa + k0 + 32); na1 = *(const uint4*)(pa + k0 + 40);
      nb0 = *(const uint4*)(pb + k0 + 32); nb1 = *(const uint4*)(pb + k0 + 40);
    }
    __syncthreads();
    *(uint4*)&sA[row*CI_LD + ho]     = a0;
    *(uint4*)&sA[row*CI_LD + ho + 8] = a1;
    *(uint4*)&sB[row*CI_LD + ho]     = b0;
    *(uint4*)&sB[row*CI_LD + ho + 8] = b1;
    __syncthreads();
    bf16x8 bfr[4];
    #pragma unroll
    for (int n = 0; n < 4; ++n)
      bfr[n] = *(const bf16x8*)&sB[(wn*64 + n*16 + l16)*CI_LD + quad*8];
    #pragma unroll
    for (int m = 0; m < 4; ++m) {
      bf16x8 af = *(const bf16x8*)&sA[(wm*64 + m*16 + l16)*CI_LD + quad*8];
      #pragma unroll
      for (int n = 0; n < 4; ++n)
        acc[m][n] = __builtin_amdgcn_mfma_f32_16x16x32_bf16(af, bfr[n], acc[m][n], 0, 0, 0);
    }
    a0 = na0; a1 = na1; b0 = nb0; b1 = nb1;
  }

  #pragma unroll
  for (int m = 0; m < 4; ++m) {
    int i = wm*64 + m*16 + quad*4;
    #pragma unroll
    for (int n = 0; n < 4; ++n) {
      int e = e0 + wn*64 + n*16 + l16;
      unsigned short* xp = X + ((size_t)b*TD_ + i)*KP_ + e;
      #pragma unroll
      for (int r = 0; r < 4; ++r)
        xp[(size_t)r*KP_] = f2bf(acc[m][n][r]);
    }
  }
}

// -- phase 4: 256x256x(BK=64) deep-phase gates GEMM + fused LSTM cell --
// A = Wr [2048][640] (rows nr = dh*4+gate), B = X [16384][640], K accumulation
// order identical to the old 32-step kernel (ks=0 then ks=1 per 64-tile).
// Staging: global_load_lds width-16, LDS linear dest + swizzled global source:
//   phys chunk pc (= lane&7) holds logical chunk pc ^ (row&7)  [involution]
// Read side applies the same XOR -> every ds_read_b128 hits all 32 banks evenly
// (8 accesses/bank: conflict-free). Loads for K-tile t+1 are issued at the top
// of tile t's compute, ~4 MFMA phases before the __syncthreads vmcnt drain.
__global__ __launch_bounds__(512, 2) void k_gates8(const unsigned short* __restrict__ Wr,
                                                   const unsigned short* __restrict__ X,
                                                   const float* __restrict__ hpre,
                                                   const float* __restrict__ m_i,
                                                   float* __restrict__ out) {
  __shared__ short lds[4 * 256 * 64];       // 128 KiB: [buf][A|B][256][64]
  const int g0  = blockIdx.x * 256;
  const int mi0 = blockIdx.y * 256;
  const int tid  = threadIdx.x;
  const int wave = tid >> 6, lane = tid & 63;
  const int l16 = lane & 15, quad = lane >> 4;
  const int wr = wave >> 2, wc = wave & 3;  // 2 x 4 wave grid, per-wave 128g x 64mi

  // staging geometry (fixed per thread)
  const int srow8 = lane >> 3;              // row within the wave's 8-row chunk
  const int sch   = (lane & 7) ^ srow8;     // pre-swizzled source chunk
  const unsigned short* gA = Wr + (size_t)(g0  + wave*8 + srow8) * KP_ + sch*8;
  const unsigned short* gB = X  + (size_t)(mi0 + wave*8 + srow8) * KP_ + sch*8;
  short* lA0 = lds;
  short* lB0 = lds + 16384;
  short* lA1 = lds + 32768;
  short* lB1 = lds + 49152;

  f32x4 acc[8][4];
  #pragma unroll
  for (int m = 0; m < 8; ++m)
    #pragma unroll
    for (int n = 0; n < 4; ++n) acc[m][n] = (f32x4){0.f, 0.f, 0.f, 0.f};

  auto stage = [&](int kt, int bf) {
    short* la = bf ? lA1 : lA0;
    short* lb = bf ? lB1 : lB0;
    const unsigned short* ga = gA + kt*64;
    const unsigned short* gb = gB + kt*64;
    #pragma unroll
    for (int r = 0; r < 4; ++r) {           // rounds: rows r*64 + wave*8 + srow8
      gload16(ga + (size_t)r*64*KP_, la + (r*8 + wave)*512);
      gload16(gb + (size_t)r*64*KP_, lb + (r*8 + wave)*512);
    }
  };

  stage(0, 0);
  __syncthreads();                           // drains vmcnt: tile 0 resident

  const int x7 = l16 & 7;
  for (int kt = 0; kt < GNT; ++kt) {
    const int cur = kt & 1;
    if (kt + 1 < GNT) stage(kt + 1, cur ^ 1);   // prefetch, 4 phases of cover
    const short* la = cur ? lA1 : lA0;
    const short* lb = cur ? lB1 : lB0;
    #pragma unroll
    for (int ks = 0; ks < 2; ++ks) {
      const int ck = ((((ks << 2) | quad) ^ x7) << 3);   // swizzled col (shorts)
      bf16x8 bv[4];
      #pragma unroll
      for (int n = 0; n < 4; ++n)
        bv[n] = *(const bf16x8*)&lb[(wc*64 + n*16 + l16)*64 + ck];
      #pragma unroll
      for (int qm = 0; qm < 2; ++qm) {
        bf16x8 av[4];
        #pragma unroll
        for (int m = 0; m < 4; ++m)
          av[m] = *(const bf16x8*)&la[(wr*128 + qm*64 + m*16 + l16)*64 + ck];
        __builtin_amdgcn_s_setprio(1);
        #pragma unroll
        for (int m = 0; m < 4; ++m)
          #pragma unroll
          for (int n = 0; n < 4; ++n)
            acc[qm*4 + m][n] = __builtin_amdgcn_mfma_f32_16x16x32_bf16(av[m], bv[n], acc[qm*4 + m][n], 0, 0, 0);
        __builtin_amdgcn_s_setprio(0);
      }
    }
    __syncthreads();   // implicit vmcnt(0): tile kt+1 landed; frees buf cur
  }

  // epilogue: lane regs r=0..3 are (ig,fg,gg,og) of one dh; b uniform per wave
  const int bb = (mi0 >> 7) + (wc >> 1);
  const float* hp = hpre + (size_t)bb * G_;
  #pragma unroll
  for (int M = 0; M < 8; ++M) {
    const int dh = (g0 >> 2) + wr*32 + M*4 + quad;
    float h0 = hp[dh], h1 = hp[DH_ + dh], h2 = hp[2*DH_ + dh], h3 = hp[3*DH_ + dh];
    float miv = m_i[(size_t)bb*DH_ + dh];
    #pragma unroll
    for (int n = 0; n < 4; ++n) {
      int mi = mi0 + wc*64 + n*16 + l16;
      float ig = acc[M][n][0] + h0;
      float fg = acc[M][n][1] + h1;
      float gg = acc[M][n][2] + h2;
      float og = acc[M][n][3] + h3;
      float c  = sigm(fg)*miv + sigm(ig)*tanhf_fast(gg);
      float h  = sigm(og)*tanhf_fast(c);
      out[(size_t)mi*DH_ + dh] = h;
    }
  }
}

extern "C" void kernel_launch(void* const* d_in, const int* in_sizes, int n_in,
                              void* d_out, int out_size, void* d_ws, size_t ws_size,
                              hipStream_t stream) {
  (void)in_sizes; (void)n_in; (void)out_size; (void)ws_size;
  const float* LSTM  = (const float*)d_in[0];
  const float* CNNs  = (const float*)d_in[1];
  const float* Wa_w  = (const float*)d_in[2];
  const float* Wa_b  = (const float*)d_in[3];
  const float* Ua_w  = (const float*)d_in[4];
  const float* Ua_b  = (const float*)d_in[5];
  const float* va_w  = (const float*)d_in[6];
  const float* va_b  = (const float*)d_in[7];
  const float* phi_w = (const float*)d_in[8];
  const float* phi_b = (const float*)d_in[9];
  const float* Wih   = (const float*)d_in[10];
  const float* Whh   = (const float*)d_in[11];
  const float* bih   = (const float*)d_in[12];
  const float* bhh   = (const float*)d_in[13];
  const float* wij_w = (const float*)d_in[14];
  const float* wij_b = (const float*)d_in[15];
  const float* s_i   = (const float*)d_in[16];
  const float* m_i   = (const float*)d_in[17];
  float* out = (float*)d_out;
  char* ws = (char*)d_ws;

  float* phi  = (float*)(ws + OFF_PHI);
  float* wa   = (float*)(ws + OFF_WA);
  float* hpre = (float*)(ws + OFF_HPRE);
  float* ep   = (float*)(ws + OFF_EP);
  float* cp   = (float*)(ws + OFF_CP);
  float* stat = (float*)(ws + OFF_STAT);
  float* ET   = (float*)(ws + OFF_ET);
  unsigned short* X  = (unsigned short*)(ws + OFF_ET);   // aliases ET (dead after k_trP)
  unsigned short* P  = (unsigned short*)(ws + OFF_P);
  unsigned short* LT = (unsigned short*)(ws + OFF_LT);
  unsigned short* Wr = (unsigned short*)(ws + OFF_WR);
  float* phiT        = (float*)(ws + OFF_PT);            // aliases P region (pre-trP)
  float* sums        = (float*)(ws + OFF_SUM);           // aliases P region
  unsigned short* Ub = (unsigned short*)(ws + OFF_UB);   // aliases P region (dead after k_bandmm)

  k_trw     <<<dim3(8,8),      dim3(256),  0, stream>>>(phi_w, phiT);
  k_phiA    <<<dim3(2,8),      dim3(256),  0, stream>>>(phiT, phi, sums);
  k_phiB    <<<dim3(2,8),      dim3(256),  0, stream>>>(sums, phi_b, phi);
  k_wa      <<<dim3(64),       dim3(256),  0, stream>>>(s_i, Wa_w, Wa_b, va_w, wa);
  k_hpre    <<<dim3(1024),     dim3(256),  0, stream>>>(s_i, Whh, bih, bhh, hpre);
  k_ep      <<<dim3(224),      dim3(256),  0, stream>>>(CNNs, wij_w, wij_b, s_i, ep);
  k_cnn_fin <<<dim3(1),        dim3(1024), 0, stream>>>(ep, CNNs, cp);
  k_cvtW    <<<dim3(640),      dim3(256),  0, stream>>>(Wih, Wr);
  k_cvtU    <<<dim3(128),      dim3(256),  0, stream>>>(Ua_w, Ub);
  k_ltrans  <<<dim3(8,8,128),  dim3(256),  0, stream>>>(LSTM, LT);
  k_bandmm  <<<dim3(8,128),    dim3(256),  0, stream>>>(LSTM, phi, Ub, Ua_b, va_w, va_b, wa, ET);
  k_stats   <<<dim3(2,128),    dim3(256),  0, stream>>>(ET, stat);
  k_trP     <<<dim3(8,2,128),  dim3(256),  0, stream>>>(ET, stat, P);
  k_cp_fill <<<dim3(1024),     dim3(256),  0, stream>>>(cp, X);
  k_ci_mm   <<<dim3(128,4),    dim3(256),  0, stream>>>(P, LT, X);
  k_gates8  <<<dim3(8,64),     dim3(512),  0, stream>>>(Wr, X, hpre, m_i, out);
}

// Round 2
// 560.985 us; speedup vs baseline: 1.1597x; 1.1597x over previous
//
#include <hip/hip_runtime.h>
#include <hip/hip_bf16.h>

#define B_   128
#define TE_  512
#define TD_  128
#define EH_  512
#define DH_  512
#define KC_  7
#define CC_  105
#define G_   2048   // 4*DH
#define KX_  617    // EH + CC
#define KP_  640    // padded K for gates GEMM
#define GNT  10     // KP_/64 K-tiles for gates GEMM

typedef __attribute__((ext_vector_type(8))) short bf16x8;
typedef __attribute__((ext_vector_type(4))) float f32x4;

__device__ __forceinline__ float sigm(float x){ return 1.f/(1.f + __expf(-x)); }
__device__ __forceinline__ float tanhf_fast(float x){
  float e = __expf(2.f*x);
  return 1.f - 2.f/(e + 1.f);
}

// fp32 -> bf16 (RNE)
__device__ __forceinline__ unsigned short f2bf(float f){
  unsigned int u = __float_as_uint(f);
  unsigned int r = (u + 0x7fffu + ((u >> 16) & 1u)) >> 16;
  return (unsigned short)r;
}

__device__ __forceinline__ float dot512f(const float* a, const float* b) {
  const float4* a4 = (const float4*)a; const float4* b4 = (const float4*)b;
  float acc = 0.f;
  #pragma unroll 8
  for (int q = 0; q < 128; ++q) {
    float4 x = a4[q], y = b4[q];
    acc += x.x*y.x + x.y*y.y + x.z*y.z + x.w*y.w;
  }
  return acc;
}

// async global->LDS, 16B per lane; LDS dest = wave-uniform base + lane*16
typedef __attribute__((address_space(3))) unsigned int lds_u32_t;
typedef __attribute__((address_space(1))) const unsigned int glb_u32_t;
__device__ __forceinline__ void gload16(const void* g, void* l) {
  __builtin_amdgcn_global_load_lds((glb_u32_t*)g, (lds_u32_t*)l, 16, 0, 0);
}

// ---------------- workspace layout (bytes) ----------------
static const size_t OFF_PHI  = 0;                                         // 1 MB
static const size_t OFF_WA   = OFF_PHI  + (size_t)TE_*EH_*4;              // 64 KB
static const size_t OFF_HPRE = OFF_WA   + (size_t)B_*TD_*4;               // 1 MB
static const size_t OFF_EP   = OFF_HPRE + (size_t)B_*G_*4;                // 4 KB
static const size_t OFF_CP   = OFF_EP   + 4096;                           // 53.8 KB
static const size_t OFF_ET   = ((OFF_CP + (size_t)B_*CC_*4 + 255)/256)*256; // 33.5 MB fp32 [b][t][i]; X bf16 aliases
static const size_t OFF_STAT = OFF_ET + (size_t)B_*TE_*TD_*4;             // 128 KB
static const size_t OFF_P    = ((OFF_STAT + (size_t)2*B_*TD_*4 + 255)/256)*256; // 16.7 MB bf16
static const size_t OFF_LT   = OFF_P  + (size_t)B_*TD_*TE_*2;             // 67 MB bf16
static const size_t OFF_WR   = OFF_LT + (size_t)B_*TE_*EH_*2;             // 2.6 MB bf16
// scratch aliases inside P region (P written later by k_trP):
static const size_t OFF_PT   = OFF_P;                                     // 1 MB fp32 phi_w^T
static const size_t OFF_SUM  = OFF_PT + (size_t)TE_*EH_*4;                // 16 KB scan sums

// ---- phi_w [e][t] -> phiT [t][e] ----
__global__ __launch_bounds__(256) void k_trw(const float* __restrict__ phi_w,
                                             float* __restrict__ phiT) {
  int e0 = blockIdx.x * 64, t0 = blockIdx.y * 64;
  __shared__ float tile[64][65];
  int tid = threadIdx.x;
  int r = tid >> 2, c16 = (tid & 3) * 16;
  const float4* src = (const float4*)(phi_w + (size_t)(e0 + r)*TE_ + t0 + c16);
  float4 v0 = src[0], v1 = src[1], v2 = src[2], v3 = src[3];
  *(float4*)&tile[r][c16]    = v0;
  *(float4*)&tile[r][c16+4]  = v1;
  *(float4*)&tile[r][c16+8]  = v2;
  *(float4*)&tile[r][c16+12] = v3;
  __syncthreads();
  float o[16];
  #pragma unroll
  for (int j = 0; j < 16; ++j) o[j] = tile[c16+j][r];
  float* dst = phiT + (size_t)(t0 + r)*EH_ + e0 + c16;
  *(float4*)dst      = *(float4*)&o[0];
  *(float4*)(dst+4)  = *(float4*)&o[4];
  *(float4*)(dst+8)  = *(float4*)&o[8];
  *(float4*)(dst+12) = *(float4*)&o[12];
}

// ---- split exclusive scan over t ----
__global__ void k_phiA(const float* __restrict__ phiT, float* __restrict__ phi,
                       float* __restrict__ sums) {
  int e = blockIdx.x * 256 + threadIdx.x;   // 512
  int z = blockIdx.y;                        // 8 chunks of 64 t
  float acc = 0.f;
  for (int t = z*64; t < z*64 + 64; ++t) {
    phi[(size_t)t*EH_ + e] = acc;
    acc += phiT[(size_t)t*EH_ + e];
  }
  sums[z*EH_ + e] = acc;
}
__global__ void k_phiB(const float* __restrict__ sums, const float* __restrict__ phi_b,
                       float* __restrict__ phi) {
  int e = blockIdx.x * 256 + threadIdx.x;
  int z = blockIdx.y;
  float off = phi_b[e];
  for (int zz = 0; zz < z; ++zz) off += sums[zz*EH_ + e];
  for (int t = z*64; t < z*64 + 64; ++t)
    phi[(size_t)t*EH_ + e] += off;
}

__global__ void k_wa(const float* __restrict__ s_i, const float* __restrict__ Wa_w,
                     const float* __restrict__ Wa_b, const float* __restrict__ va_w,
                     float* __restrict__ wa) {
  int id = blockIdx.x * blockDim.x + threadIdx.x;  // 16384
  int b = id >> 7, d = id & 127;
  float acc = Wa_b[d] + dot512f(s_i + (size_t)b*DH_, Wa_w + (size_t)d*DH_);
  wa[id] = tanhf_fast(acc) * va_w[d];
}

__global__ void k_hpre(const float* __restrict__ s_i, const float* __restrict__ Whh,
                       const float* __restrict__ bih, const float* __restrict__ bhh,
                       float* __restrict__ hpre) {
  int id = blockIdx.x * blockDim.x + threadIdx.x; // 262144
  int b = id >> 11, g = id & 2047;
  hpre[id] = bih[g] + bhh[g] + dot512f(s_i + (size_t)b*DH_, Whh + (size_t)g*DH_);
}

// ---- ep: one wave per (b,k) ----
__global__ __launch_bounds__(256) void k_ep(const float* __restrict__ CNNs,
                                            const float* __restrict__ wij_w,
                                            const float* __restrict__ wij_b,
                                            const float* __restrict__ s_i,
                                            float* __restrict__ ep) {
  int gw = blockIdx.x * 4 + (threadIdx.x >> 6);
  int lane = threadIdx.x & 63;
  if (gw >= B_*KC_) return;
  int b = gw / KC_, k = gw % KC_;
  const float* cr = CNNs + (size_t)(b*KC_ + k)*CC_;
  const float* wr = wij_w + (size_t)k*KX_;
  float acc = 0.f;
  for (int c = lane; c < CC_; c += 64) acc += cr[c] * wr[c];
  const float* sr = s_i + (size_t)b*DH_;
  const float* wsr = wr + CC_;
  #pragma unroll
  for (int j = 0; j < 8; ++j) { int h = lane + j*64; acc += sr[h] * wsr[h]; }
  #pragma unroll
  for (int m = 32; m; m >>= 1) acc += __shfl_xor(acc, m, 64);
  if (lane == 0) ep[gw] = tanhf_fast(acc + wij_b[k]);
}

__global__ void k_cnn_fin(const float* __restrict__ ep, const float* __restrict__ CNNs,
                          float* __restrict__ cp) {
  __shared__ float red[1024];
  __shared__ float apl[B_*KC_];
  int tid = threadIdx.x;
  red[tid] = (tid < B_*KC_) ? ep[tid] : 0.f;
  __syncthreads();
  for (int off = 512; off > 0; off >>= 1) {
    if (tid < off) red[tid] += red[tid + off];
    __syncthreads();
  }
  float S = red[0];
  if (tid < B_*KC_) apl[tid] = __expf(ep[tid]) / S;   // ref: exp(ep)/sum(ep), GLOBAL sum
  __syncthreads();
  for (int idx = tid; idx < B_*CC_; idx += blockDim.x) {
    int b = idx / CC_, c = idx % CC_;
    float acc = 0.f;
    #pragma unroll
    for (int k = 0; k < KC_; ++k)
      acc += apl[b*KC_ + k] * CNNs[(size_t)(b*KC_ + k)*CC_ + c];
    cp[idx] = acc;
  }
}

// ---- Wih fp32 -> bf16 [2048][640], rows reordered nr = dh*4+gate ----
__global__ void k_cvtW(const float* __restrict__ Wih, unsigned short* __restrict__ Wr) {
  int id = blockIdx.x * 256 + threadIdx.x;    // 2048*80
  int nr = id / 80, c8 = (id % 80) * 8;
  int gate = nr & 3, dh = nr >> 2;
  const float* src = Wih + (size_t)(gate*DH_ + dh)*KX_;
  unsigned short o[8];
  #pragma unroll
  for (int j = 0; j < 8; ++j) {
    int col = c8 + j;
    o[j] = (col < KX_) ? f2bf(src[col]) : 0;
  }
  *(uint4*)(Wr + (size_t)nr*KP_ + c8) = *(uint4*)o;
}

// ---- LSTM [b][t][e] fp32 -> LT [b][e][t] bf16 ----
__global__ __launch_bounds__(256) void k_ltrans(const float* __restrict__ LSTM,
                                                unsigned short* __restrict__ LT) {
  int e0 = blockIdx.x * 64, t0 = blockIdx.y * 64, b = blockIdx.z;
  __shared__ float tile[64][65];
  int tid = threadIdx.x;
  int tt = tid >> 2, c16 = (tid & 3) * 16;
  const float4* src = (const float4*)(LSTM + ((size_t)b*TE_ + t0 + tt)*EH_ + e0 + c16);
  float4 v0 = src[0], v1 = src[1], v2 = src[2], v3 = src[3];
  *(float4*)&tile[tt][c16]    = v0;
  *(float4*)&tile[tt][c16+4]  = v1;
  *(float4*)&tile[tt][c16+8]  = v2;
  *(float4*)&tile[tt][c16+12] = v3;
  __syncthreads();
  int e = tid >> 2, t16 = (tid & 3) * 16;
  unsigned short o[16];
  #pragma unroll
  for (int j = 0; j < 16; ++j) o[j] = f2bf(tile[t16+j][e]);
  unsigned short* dst = LT + ((size_t)b*EH_ + e0 + e)*TE_ + t0 + t16;
  *(uint4*)dst     = *(uint4*)&o[0];
  *(uint4*)(dst+8) = *(uint4*)&o[8];
}

// ---------- phase 1: banded logits MFMA band-GEMM ----------
// K-loop: round-0 proven operand path (fp32 Ua_w + in-kernel f2bf).
// Epilogue: band values scattered into an LDS fp32 tile (aliasing dead sA/sB),
// then cooperatively stored as aligned float4 -> each HBM line written once
// (round-1 counters showed 229MB WRITE_SIZE for a 33.5MB logical output).
#define BMM_M 64
#define LDA_  40
#define LDB_  40
#define OTS_  132   // tile row stride in floats (528B: 16B-aligned, low LDS conflict)
__global__ __launch_bounds__(256) void k_bandmm(const float* __restrict__ LSTM,
                                                const float* __restrict__ phi,
                                                const float* __restrict__ Ua_w,
                                                const float* __restrict__ Ua_b,
                                                const float* __restrict__ va_w,
                                                const float* __restrict__ va_b,
                                                const float* __restrict__ wa,
                                                float* __restrict__ ET) {
  int t0 = blockIdx.x * BMM_M;   // 8 tiles
  int b  = blockIdx.y;           // 128
  int s_base = 321 - t0;
  __shared__ __align__(16) char smem[BMM_M * OTS_ * 4];   // 33.8 KB
  short* sA = (short*)smem;                 // [64][40]
  short* sB = (short*)(smem + BMM_M*LDA_*2);// [192][40]
  int tid = threadIdx.x;
  int wave = tid >> 6, lane = tid & 63;
  int quad = lane >> 4, l16 = lane & 15;

  f32x4 acc[4][3];
  #pragma unroll
  for (int m = 0; m < 4; ++m)
    #pragma unroll
    for (int n = 0; n < 3; ++n)
      acc[m][n] = (f32x4){0.f, 0.f, 0.f, 0.f};

  int arow = tid >> 2;             // 0..63
  int ach  = (tid & 3) * 8;        // shorts
  int aq   = ach >> 2;             // float4 units

  const float4* baseL = (const float4*)(LSTM + ((size_t)b*TE_ + t0 + arow)*EH_);
  const float4* baseP = (const float4*)(phi + (size_t)(t0 + arow)*EH_);
  const float4* baseU[3];
  int brow[3], bch[3];
  #pragma unroll
  for (int c = 0; c < 3; ++c) {
    int idx = c*256 + tid;
    brow[c] = idx >> 2;
    bch[c]  = (idx & 3) * 8;
    int s = s_base + brow[c];
    int sc = s < 0 ? 0 : (s > 511 ? 511 : s);
    baseU[c] = (const float4*)(Ua_w + (size_t)sc*EH_ + bch[c]);
  }

  float4 l0 = baseL[aq], l1 = baseL[aq+1], p0 = baseP[aq], p1 = baseP[aq+1];
  float4 u0[3], u1[3];
  #pragma unroll
  for (int c = 0; c < 3; ++c) { u0[c] = baseU[c][0]; u1[c] = baseU[c][1]; }

  for (int k0 = 0; k0 < EH_; k0 += 32) {
    unsigned short at[8];
    at[0]=f2bf(l0.x*p0.x); at[1]=f2bf(l0.y*p0.y); at[2]=f2bf(l0.z*p0.z); at[3]=f2bf(l0.w*p0.w);
    at[4]=f2bf(l1.x*p1.x); at[5]=f2bf(l1.y*p1.y); at[6]=f2bf(l1.z*p1.z); at[7]=f2bf(l1.w*p1.w);
    unsigned short bt[3][8];
    #pragma unroll
    for (int c = 0; c < 3; ++c) {
      bt[c][0]=f2bf(u0[c].x); bt[c][1]=f2bf(u0[c].y); bt[c][2]=f2bf(u0[c].z); bt[c][3]=f2bf(u0[c].w);
      bt[c][4]=f2bf(u1[c].x); bt[c][5]=f2bf(u1[c].y); bt[c][6]=f2bf(u1[c].z); bt[c][7]=f2bf(u1[c].w);
    }
    if (k0 + 32 < EH_) {                       // prefetch next chunk
      int q = (k0 + 32) >> 2;
      l0 = baseL[q+aq]; l1 = baseL[q+aq+1]; p0 = baseP[q+aq]; p1 = baseP[q+aq+1];
      #pragma unroll
      for (int c = 0; c < 3; ++c) { u0[c] = baseU[c][q]; u1[c] = baseU[c][q+1]; }
    }
    __syncthreads();
    *(uint4*)&sA[arow*LDA_ + ach] = *(uint4*)at;
    #pragma unroll
    for (int c = 0; c < 3; ++c)
      *(uint4*)&sB[brow[c]*LDB_ + bch[c]] = *(uint4*)bt[c];
    __syncthreads();
    bf16x8 bfr[3];
    #pragma unroll
    for (int n = 0; n < 3; ++n)
      bfr[n] = *(const bf16x8*)&sB[(l16 + (wave*3 + n)*16)*LDB_ + quad*8];
    #pragma unroll
    for (int m = 0; m < 4; ++m) {
      bf16x8 af = *(const bf16x8*)&sA[(l16 + m*16)*LDA_ + quad*8];
      #pragma unroll
      for (int n = 0; n < 3; ++n)
        acc[m][n] = __builtin_amdgcn_mfma_f32_16x16x32_bf16(af, bfr[n], acc[m][n], 0, 0, 0);
    }
  }

  __syncthreads();                 // sA/sB dead -> reuse smem as output tile
  float* tileO = (float*)smem;     // [64][OTS_]
  float vb = va_b[0];
  #pragma unroll
  for (int n = 0; n < 3; ++n) {
    int s = s_base + wave*48 + n*16 + l16;
    float ub = (s >= 0 && s < TE_) ? Ua_b[s] : 0.f;
    float vw = (s >= 0 && s < TE_) ? va_w[TD_ + s] : 0.f;
    #pragma unroll
    for (int m = 0; m < 4; ++m) {
      #pragma unroll
      for (int r = 0; r < 4; ++r) {
        int tl = m*16 + quad*4 + r;        // t - t0
        int i = s + t0 + tl - 384;
        if (i >= 0 && i < TD_) {
          float val;
          if (s >= 0) val = tanhf_fast(acc[m][n][r] + ub) * vw + vb;
          else        val = wa[b*TD_ + s + 128] + vb;
          tileO[tl*OTS_ + i] = val;
        }
      }
    }
  }
  __syncthreads();
  // cooperative aligned store: 64 rows x 128 floats, every line written once
  {
    int rsub = tid >> 5, c4 = (tid & 31) * 4;
    #pragma unroll
    for (int p = 0; p < 8; ++p) {
      int row = p*8 + rsub;
      float4 v = *(const float4*)&tileO[row*OTS_ + c4];
      *(float4*)(ET + ((size_t)b*TE_ + t0 + row)*TD_ + c4) = v;
    }
  }
}

// ---------------- phase 2: softmax stats over t ----------------
__global__ __launch_bounds__(256) void k_stats(const float* __restrict__ ET,
                                               float* __restrict__ stat) {
  int i0 = blockIdx.x * 64, b = blockIdx.y;
  __shared__ float red[4][64], smax[64];
  int tid = threadIdx.x;
  int q = tid >> 6, il = tid & 63;
  const float* col = ET + (size_t)b*TE_*TD_ + i0 + il;
  float m = -1e30f;
  for (int t = q*128; t < q*128 + 128; ++t) m = fmaxf(m, col[(size_t)t*TD_]);
  red[q][il] = m;
  __syncthreads();
  if (tid < 64) {
    float mm = fmaxf(fmaxf(red[0][tid], red[1][tid]), fmaxf(red[2][tid], red[3][tid]));
    smax[tid] = mm;
  }
  __syncthreads();
  float mm = smax[il];
  float s = 0.f;
  for (int t = q*128; t < q*128 + 128; ++t) s += __expf(col[(size_t)t*TD_] - mm);
  __syncthreads();
  red[q][il] = s;
  __syncthreads();
  if (tid < 64) {
    float ss = red[0][tid] + red[1][tid] + red[2][tid] + red[3][tid];
    stat[b*TD_ + i0 + tid] = smax[tid];
    stat[(size_t)B_*TD_ + b*TD_ + i0 + tid] = 1.f/ss;
  }
}

// ---- ET [b][t][i] + stats -> P [b][i][t] bf16 (softmax applied, transposed) ----
__global__ __launch_bounds__(256) void k_trP(const float* __restrict__ ET,
                                             const float* __restrict__ stat,
                                             unsigned short* __restrict__ P) {
  int t0 = blockIdx.x * 64, i0 = blockIdx.y * 64, b = blockIdx.z;
  __shared__ float tile[64][65];
  __shared__ float smL[64], svL[64];
  int tid = threadIdx.x;
  if (tid < 64) {
    smL[tid] = stat[b*TD_ + i0 + tid];
    svL[tid] = stat[(size_t)B_*TD_ + b*TD_ + i0 + tid];
  }
  int tt = tid >> 2, c16 = (tid & 3) * 16;
  const float4* src = (const float4*)(ET + ((size_t)b*TE_ + t0 + tt)*TD_ + i0 + c16);
  float4 v[4]; v[0] = src[0]; v[1] = src[1]; v[2] = src[2]; v[3] = src[3];
  __syncthreads();
  const float* vf = (const float*)v;
  #pragma unroll
  for (int j = 0; j < 16; ++j)
    tile[tt][c16+j] = __expf(vf[j] - smL[c16+j]) * svL[c16+j];
  __syncthreads();
  int i = tid >> 2, t16 = (tid & 3) * 16;
  unsigned short o[16];
  #pragma unroll
  for (int j = 0; j < 16; ++j) o[j] = f2bf(tile[t16+j][i]);
  unsigned short* dst = P + ((size_t)b*TD_ + i0 + i)*TE_ + t0 + t16;
  *(uint4*)dst     = *(uint4*)&o[0];
  *(uint4*)(dst+8) = *(uint4*)&o[8];
}

// ---- fill X[:,512:640] from cp (bf16), zero pad ----
__global__ void k_cp_fill(const float* __restrict__ cp, unsigned short* __restrict__ X) {
  int id = blockIdx.x * 256 + threadIdx.x;  // 16384*16
  int m = id >> 4, c8 = (id & 15) * 8;
  int b = m >> 7;
  unsigned short o[8];
  #pragma unroll
  for (int j = 0; j < 8; ++j) {
    int c = c8 + j;
    o[j] = (c < CC_) ? f2bf(cp[b*CC_ + c]) : 0;
  }
  *(uint4*)(X + (size_t)m*KP_ + EH_ + c8) = *(uint4*)o;
}

// ------ phase 3 (MFMA, BK=32): X[b*128+i][e] = sum_t P[b][i][t]*LT[b][e][t] ------
#define CI_LD 40
__global__ __launch_bounds__(256) void k_ci_mm(const unsigned short* __restrict__ P,
                                               const unsigned short* __restrict__ LT,
                                               unsigned short* __restrict__ X) {
  int b = blockIdx.x, e0 = blockIdx.y * 128;
  __shared__ short sA[128 * CI_LD];
  __shared__ short sB[128 * CI_LD];
  int tid = threadIdx.x;
  int wave = tid >> 6, lane = tid & 63, quad = lane >> 4, l16 = lane & 15;
  int wm = wave >> 1, wn = wave & 1;
  int row = tid >> 1, ho = (tid & 1) * 16;

  const unsigned short* pa = P + ((size_t)b*TD_ + row)*TE_ + ho;
  const unsigned short* pb = LT + ((size_t)b*EH_ + e0 + row)*TE_ + ho;

  f32x4 acc[4][4];
  #pragma unroll
  for (int m = 0; m < 4; ++m)
    #pragma unroll
    for (int n = 0; n < 4; ++n)
      acc[m][n] = (f32x4){0.f, 0.f, 0.f, 0.f};

  uint4 a0 = *(const uint4*)pa, a1 = *(const uint4*)(pa + 8);
  uint4 b0 = *(const uint4*)pb, b1 = *(const uint4*)(pb + 8);

  for (int k0 = 0; k0 < TE_; k0 += 32) {
    uint4 na0, na1, nb0, nb1;
    if (k0 + 32 < TE_) {
      na0 = *(const uint4*)(pa + k0 + 32); na1 = *(const uint4*)(pa + k0 + 40);
      nb0 = *(const uint4*)(pb + k0 + 32); nb1 = *(const uint4*)(pb + k0 + 40);
    }
    __syncthreads();
    *(uint4*)&sA[row*CI_LD + ho]     = a0;
    *(uint4*)&sA[row*CI_LD + ho + 8] = a1;
    *(uint4*)&sB[row*CI_LD + ho]     = b0;
    *(uint4*)&sB[row*CI_LD + ho + 8] = b1;
    __syncthreads();
    bf16x8 bfr[4];
    #pragma unroll
    for (int n = 0; n < 4; ++n)
      bfr[n] = *(const bf16x8*)&sB[(wn*64 + n*16 + l16)*CI_LD + quad*8];
    #pragma unroll
    for (int m = 0; m < 4; ++m) {
      bf16x8 af = *(const bf16x8*)&sA[(wm*64 + m*16 + l16)*CI_LD + quad*8];
      #pragma unroll
      for (int n = 0; n < 4; ++n)
        acc[m][n] = __builtin_amdgcn_mfma_f32_16x16x32_bf16(af, bfr[n], acc[m][n], 0, 0, 0);
    }
    a0 = na0; a1 = na1; b0 = nb0; b1 = nb1;
  }

  #pragma unroll
  for (int m = 0; m < 4; ++m) {
    int i = wm*64 + m*16 + quad*4;
    #pragma unroll
    for (int n = 0; n < 4; ++n) {
      int e = e0 + wn*64 + n*16 + l16;
      unsigned short* xp = X + ((size_t)b*TD_ + i)*KP_ + e;
      #pragma unroll
      for (int r = 0; r < 4; ++r)
        xp[(size_t)r*KP_] = f2bf(acc[m][n][r]);
    }
  }
}

// -- phase 4: 256x256x(BK=64) deep-phase gates GEMM + fused LSTM cell --
__global__ __launch_bounds__(512, 2) void k_gates8(const unsigned short* __restrict__ Wr,
                                                   const unsigned short* __restrict__ X,
                                                   const float* __restrict__ hpre,
                                                   const float* __restrict__ m_i,
                                                   float* __restrict__ out) {
  __shared__ short lds[4 * 256 * 64];       // 128 KiB: [buf][A|B][256][64]
  const int g0  = blockIdx.x * 256;
  const int mi0 = blockIdx.y * 256;
  const int tid  = threadIdx.x;
  const int wave = tid >> 6, lane = tid & 63;
  const int l16 = lane & 15, quad = lane >> 4;
  const int wr = wave >> 2, wc = wave & 3;  // 2 x 4 wave grid, per-wave 128g x 64mi

  // staging geometry (fixed per thread)
  const int srow8 = lane >> 3;              // row within the wave's 8-row chunk
  const int sch   = (lane & 7) ^ srow8;     // pre-swizzled source chunk
  const unsigned short* gA = Wr + (size_t)(g0  + wave*8 + srow8) * KP_ + sch*8;
  const unsigned short* gB = X  + (size_t)(mi0 + wave*8 + srow8) * KP_ + sch*8;
  short* lA0 = lds;
  short* lB0 = lds + 16384;
  short* lA1 = lds + 32768;
  short* lB1 = lds + 49152;

  f32x4 acc[8][4];
  #pragma unroll
  for (int m = 0; m < 8; ++m)
    #pragma unroll
    for (int n = 0; n < 4; ++n) acc[m][n] = (f32x4){0.f, 0.f, 0.f, 0.f};

  auto stage = [&](int kt, int bf) {
    short* la = bf ? lA1 : lA0;
    short* lb = bf ? lB1 : lB0;
    const unsigned short* ga = gA + kt*64;
    const unsigned short* gb = gB + kt*64;
    #pragma unroll
    for (int r = 0; r < 4; ++r) {           // rounds: rows r*64 + wave*8 + srow8
      gload16(ga + (size_t)r*64*KP_, la + (r*8 + wave)*512);
      gload16(gb + (size_t)r*64*KP_, lb + (r*8 + wave)*512);
    }
  };

  stage(0, 0);
  __syncthreads();                           // drains vmcnt: tile 0 resident

  const int x7 = l16 & 7;
  for (int kt = 0; kt < GNT; ++kt) {
    const int cur = kt & 1;
    if (kt + 1 < GNT) stage(kt + 1, cur ^ 1);   // prefetch, 4 phases of cover
    const short* la = cur ? lA1 : lA0;
    const short* lb = cur ? lB1 : lB0;
    #pragma unroll
    for (int ks = 0; ks < 2; ++ks) {
      const int ck = ((((ks << 2) | quad) ^ x7) << 3);   // swizzled col (shorts)
      bf16x8 bv[4];
      #pragma unroll
      for (int n = 0; n < 4; ++n)
        bv[n] = *(const bf16x8*)&lb[(wc*64 + n*16 + l16)*64 + ck];
      #pragma unroll
      for (int qm = 0; qm < 2; ++qm) {
        bf16x8 av[4];
        #pragma unroll
        for (int m = 0; m < 4; ++m)
          av[m] = *(const bf16x8*)&la[(wr*128 + qm*64 + m*16 + l16)*64 + ck];
        __builtin_amdgcn_s_setprio(1);
        #pragma unroll
        for (int m = 0; m < 4; ++m)
          #pragma unroll
          for (int n = 0; n < 4; ++n)
            acc[qm*4 + m][n] = __builtin_amdgcn_mfma_f32_16x16x32_bf16(av[m], bv[n], acc[qm*4 + m][n], 0, 0, 0);
        __builtin_amdgcn_s_setprio(0);
      }
    }
    __syncthreads();   // implicit vmcnt(0): tile kt+1 landed; frees buf cur
  }

  // epilogue: lane regs r=0..3 are (ig,fg,gg,og) of one dh; b uniform per wave
  const int bb = (mi0 >> 7) + (wc >> 1);
  const float* hp = hpre + (size_t)bb * G_;
  #pragma unroll
  for (int M = 0; M < 8; ++M) {
    const int dh = (g0 >> 2) + wr*32 + M*4 + quad;
    float h0 = hp[dh], h1 = hp[DH_ + dh], h2 = hp[2*DH_ + dh], h3 = hp[3*DH_ + dh];
    float miv = m_i[(size_t)bb*DH_ + dh];
    #pragma unroll
    for (int n = 0; n < 4; ++n) {
      int mi = mi0 + wc*64 + n*16 + l16;
      float ig = acc[M][n][0] + h0;
      float fg = acc[M][n][1] + h1;
      float gg = acc[M][n][2] + h2;
      float og = acc[M][n][3] + h3;
      float c  = sigm(fg)*miv + sigm(ig)*tanhf_fast(gg);
      float h  = sigm(og)*tanhf_fast(c);
      out[(size_t)mi*DH_ + dh] = h;
    }
  }
}

extern "C" void kernel_launch(void* const* d_in, const int* in_sizes, int n_in,
                              void* d_out, int out_size, void* d_ws, size_t ws_size,
                              hipStream_t stream) {
  (void)in_sizes; (void)n_in; (void)out_size; (void)ws_size;
  const float* LSTM  = (const float*)d_in[0];
  const float* CNNs  = (const float*)d_in[1];
  const float* Wa_w  = (const float*)d_in[2];
  const float* Wa_b  = (const float*)d_in[3];
  const float* Ua_w  = (const float*)d_in[4];
  const float* Ua_b  = (const float*)d_in[5];
  const float* va_w  = (const float*)d_in[6];
  const float* va_b  = (const float*)d_in[7];
  const float* phi_w = (const float*)d_in[8];
  const float* phi_b = (const float*)d_in[9];
  const float* Wih   = (const float*)d_in[10];
  const float* Whh   = (const float*)d_in[11];
  const float* bih   = (const float*)d_in[12];
  const float* bhh   = (const float*)d_in[13];
  const float* wij_w = (const float*)d_in[14];
  const float* wij_b = (const float*)d_in[15];
  const float* s_i   = (const float*)d_in[16];
  const float* m_i   = (const float*)d_in[17];
  float* out = (float*)d_out;
  char* ws = (char*)d_ws;

  float* phi  = (float*)(ws + OFF_PHI);
  float* wa   = (float*)(ws + OFF_WA);
  float* hpre = (float*)(ws + OFF_HPRE);
  float* ep   = (float*)(ws + OFF_EP);
  float* cp   = (float*)(ws + OFF_CP);
  float* stat = (float*)(ws + OFF_STAT);
  float* ET   = (float*)(ws + OFF_ET);
  unsigned short* X  = (unsigned short*)(ws + OFF_ET);   // aliases ET (dead after k_trP)
  unsigned short* P  = (unsigned short*)(ws + OFF_P);
  unsigned short* LT = (unsigned short*)(ws + OFF_LT);
  unsigned short* Wr = (unsigned short*)(ws + OFF_WR);
  float* phiT        = (float*)(ws + OFF_PT);            // aliases P region (pre-trP)
  float* sums        = (float*)(ws + OFF_SUM);           // aliases P region

  k_trw     <<<dim3(8,8),      dim3(256),  0, stream>>>(phi_w, phiT);
  k_phiA    <<<dim3(2,8),      dim3(256),  0, stream>>>(phiT, phi, sums);
  k_phiB    <<<dim3(2,8),      dim3(256),  0, stream>>>(sums, phi_b, phi);
  k_wa      <<<dim3(64),       dim3(256),  0, stream>>>(s_i, Wa_w, Wa_b, va_w, wa);
  k_hpre    <<<dim3(1024),     dim3(256),  0, stream>>>(s_i, Whh, bih, bhh, hpre);
  k_ep      <<<dim3(224),      dim3(256),  0, stream>>>(CNNs, wij_w, wij_b, s_i, ep);
  k_cnn_fin <<<dim3(1),        dim3(1024), 0, stream>>>(ep, CNNs, cp);
  k_cvtW    <<<dim3(640),      dim3(256),  0, stream>>>(Wih, Wr);
  k_ltrans  <<<dim3(8,8,128),  dim3(256),  0, stream>>>(LSTM, LT);
  k_bandmm  <<<dim3(8,128),    dim3(256),  0, stream>>>(LSTM, phi, Ua_w, Ua_b, va_w, va_b, wa, ET);
  k_stats   <<<dim3(2,128),    dim3(256),  0, stream>>>(ET, stat);
  k_trP     <<<dim3(8,2,128),  dim3(256),  0, stream>>>(ET, stat, P);
  k_cp_fill <<<dim3(1024),     dim3(256),  0, stream>>>(cp, X);
  k_ci_mm   <<<dim3(128,4),    dim3(256),  0, stream>>>(P, LT, X);
  k_gates8  <<<dim3(8,64),     dim3(512),  0, stream>>>(Wr, X, hpre, m_i, out);
}

// Round 3
// 532.622 us; speedup vs baseline: 1.2214x; 1.0533x over previous
//
#include <hip/hip_runtime.h>
#include <hip/hip_bf16.h>

#define B_   128
#define TE_  512
#define TD_  128
#define EH_  512
#define DH_  512
#define KC_  7
#define CC_  105
#define G_   2048   // 4*DH
#define KX_  617    // EH + CC
#define KP_  640    // padded K for gates GEMM
#define GNT  10     // KP_/64 K-tiles for gates GEMM

typedef __attribute__((ext_vector_type(8))) short bf16x8;
typedef __attribute__((ext_vector_type(4))) float f32x4;

__device__ __forceinline__ float sigm(float x){ return 1.f/(1.f + __expf(-x)); }
__device__ __forceinline__ float tanhf_fast(float x){
  float e = __expf(2.f*x);
  return 1.f - 2.f/(e + 1.f);
}

// fp32 -> bf16 (RNE)
__device__ __forceinline__ unsigned short f2bf(float f){
  unsigned int u = __float_as_uint(f);
  unsigned int r = (u + 0x7fffu + ((u >> 16) & 1u)) >> 16;
  return (unsigned short)r;
}

// async global->LDS, 16B per lane; LDS dest = wave-uniform base + lane*16
typedef __attribute__((address_space(3))) unsigned int lds_u32_t;
typedef __attribute__((address_space(1))) const unsigned int glb_u32_t;
__device__ __forceinline__ void gload16(const void* g, void* l) {
  __builtin_amdgcn_global_load_lds((glb_u32_t*)g, (lds_u32_t*)l, 16, 0, 0);
}

// ---------------- workspace layout (bytes) ----------------
static const size_t OFF_PHI  = 0;                                         // 1 MB
static const size_t OFF_WA   = OFF_PHI  + (size_t)TE_*EH_*4;              // 64 KB
static const size_t OFF_HPRE = OFF_WA   + (size_t)B_*TD_*4;               // 1 MB
static const size_t OFF_EP   = OFF_HPRE + (size_t)B_*G_*4;                // 4 KB
static const size_t OFF_CP   = OFF_EP   + 4096;                           // 53.8 KB
static const size_t OFF_ET   = ((OFF_CP + (size_t)B_*CC_*4 + 255)/256)*256; // 33.5 MB fp32 [b][t][i]; X bf16 aliases
static const size_t OFF_STAT = OFF_ET + (size_t)B_*TE_*TD_*4;             // 128 KB
static const size_t OFF_P    = ((OFF_STAT + (size_t)2*B_*TD_*4 + 255)/256)*256; // 16.7 MB bf16
static const size_t OFF_LT   = OFF_P  + (size_t)B_*TD_*TE_*2;             // 67 MB bf16
static const size_t OFF_WR   = OFF_LT + (size_t)B_*TE_*EH_*2;             // 2.6 MB bf16
// scratch aliases inside P region (P written later by k_trP; all dead by then):
static const size_t OFF_PT   = OFF_P;                                     // 1 MB fp32 phi_w^T
static const size_t OFF_SUM  = OFF_PT + (size_t)TE_*EH_*4;                // 16 KB scan sums
static const size_t OFF_WT   = OFF_P + (size_t)2*1024*1024;               // 4 MB Whh^T fp32
static const size_t OFF_WAT  = OFF_P + (size_t)6*1024*1024;               // 256 KB Wa_w^T fp32

// ---- generic fp32 transpose: src[R][C] -> dst[C][R], 64x64 tiles ----
__global__ __launch_bounds__(256) void k_tr(const float* __restrict__ src,
                                            float* __restrict__ dst, int R, int C) {
  int r0 = blockIdx.x * 64, c0 = blockIdx.y * 64;
  __shared__ float tile[64][65];
  int tid = threadIdx.x;
  int r = tid >> 2, c16 = (tid & 3) * 16;
  const float4* s4 = (const float4*)(src + (size_t)(r0 + r)*C + c0 + c16);
  float4 v0 = s4[0], v1 = s4[1], v2 = s4[2], v3 = s4[3];
  *(float4*)&tile[r][c16]    = v0;
  *(float4*)&tile[r][c16+4]  = v1;
  *(float4*)&tile[r][c16+8]  = v2;
  *(float4*)&tile[r][c16+12] = v3;
  __syncthreads();
  float o[16];
  #pragma unroll
  for (int j = 0; j < 16; ++j) o[j] = tile[c16+j][r];
  float* d = dst + (size_t)(c0 + r)*R + r0 + c16;
  *(float4*)d      = *(float4*)&o[0];
  *(float4*)(d+4)  = *(float4*)&o[4];
  *(float4*)(d+8)  = *(float4*)&o[8];
  *(float4*)(d+12) = *(float4*)&o[12];
}

// ---- split exclusive scan over t ----
__global__ void k_phiA(const float* __restrict__ phiT, float* __restrict__ phi,
                       float* __restrict__ sums) {
  int e = blockIdx.x * 256 + threadIdx.x;   // 512
  int z = blockIdx.y;                        // 8 chunks of 64 t
  float acc = 0.f;
  for (int t = z*64; t < z*64 + 64; ++t) {
    phi[(size_t)t*EH_ + e] = acc;
    acc += phiT[(size_t)t*EH_ + e];
  }
  sums[z*EH_ + e] = acc;
}
__global__ void k_phiB(const float* __restrict__ sums, const float* __restrict__ phi_b,
                       float* __restrict__ phi) {
  int e = blockIdx.x * 256 + threadIdx.x;
  int z = blockIdx.y;
  float off = phi_b[e];
  for (int zz = 0; zz < z; ++zz) off += sums[zz*EH_ + e];
  for (int t = z*64; t < z*64 + 64; ++t)
    phi[(size_t)t*EH_ + e] += off;
}

// ---- wa[b][d] = tanh(s_i[b]·Wa_w[d] + Wa_b[d]) * va_w[d], coalesced via WaT ----
__global__ __launch_bounds__(256) void k_wa2(const float* __restrict__ s_i,
                                             const float* __restrict__ WaT,
                                             const float* __restrict__ Wa_b,
                                             const float* __restrict__ va_w,
                                             float* __restrict__ wa) {
  int lane = threadIdx.x & 63, wv = threadIdx.x >> 6;
  int b = blockIdx.x * 4 + wv;               // 32 blocks x 4 waves = 128 b
  int d0 = lane * 2;
  const float2* w = (const float2*)WaT + lane;   // row stride 64 float2
  const float* s = s_i + (size_t)b*DH_;
  float ax = 0.f, ay = 0.f;
  #pragma unroll 8
  for (int k = 0; k < DH_; ++k) {
    float2 wv2 = w[(size_t)k*64];
    float x = s[k];
    ax += wv2.x * x; ay += wv2.y * x;
  }
  wa[b*TD_ + d0]     = tanhf_fast(ax + Wa_b[d0])     * va_w[d0];
  wa[b*TD_ + d0 + 1] = tanhf_fast(ay + Wa_b[d0 + 1]) * va_w[d0 + 1];
}

// ---- hpre[b][g] = bih[g]+bhh[g] + s_i[b]·Whh[g], coalesced via WhhT ----
// thread = 4 g (float4 from WhhT row) x 2 b (block-uniform scalars -> s_load).
__global__ __launch_bounds__(64) void k_hpre2(const float* __restrict__ s_i,
                                              const float* __restrict__ WhhT,
                                              const float* __restrict__ bih,
                                              const float* __restrict__ bhh,
                                              float* __restrict__ hpre) {
  int gq = blockIdx.x * 64 + threadIdx.x;    // 0..511 float4-group of g
  int b0 = blockIdx.y * 2;                   // 64 b-pairs
  const float4* w = (const float4*)WhhT + gq;    // row stride 512 float4
  const float* s0 = s_i + (size_t)b0*DH_;
  const float* s1 = s0 + DH_;
  float4 a0 = {0.f,0.f,0.f,0.f}, a1 = {0.f,0.f,0.f,0.f};
  #pragma unroll 8
  for (int k = 0; k < DH_; ++k) {
    float4 wv = w[(size_t)k*512];
    float x0 = s0[k], x1 = s1[k];
    a0.x += wv.x*x0; a0.y += wv.y*x0; a0.z += wv.z*x0; a0.w += wv.w*x0;
    a1.x += wv.x*x1; a1.y += wv.y*x1; a1.z += wv.z*x1; a1.w += wv.w*x1;
  }
  int g = gq * 4;
  float4 bi = *(const float4*)(bih + g);
  float4 bh = *(const float4*)(bhh + g);
  float4 o0, o1;
  o0.x = a0.x + bi.x + bh.x; o0.y = a0.y + bi.y + bh.y;
  o0.z = a0.z + bi.z + bh.z; o0.w = a0.w + bi.w + bh.w;
  o1.x = a1.x + bi.x + bh.x; o1.y = a1.y + bi.y + bh.y;
  o1.z = a1.z + bi.z + bh.z; o1.w = a1.w + bi.w + bh.w;
  *(float4*)(hpre + (size_t)b0*G_ + g)       = o0;
  *(float4*)(hpre + (size_t)(b0+1)*G_ + g)   = o1;
}

// ---- ep: one wave per (b,k) ----
__global__ __launch_bounds__(256) void k_ep(const float* __restrict__ CNNs,
                                            const float* __restrict__ wij_w,
                                            const float* __restrict__ wij_b,
                                            const float* __restrict__ s_i,
                                            float* __restrict__ ep) {
  int gw = blockIdx.x * 4 + (threadIdx.x >> 6);
  int lane = threadIdx.x & 63;
  if (gw >= B_*KC_) return;
  int b = gw / KC_, k = gw % KC_;
  const float* cr = CNNs + (size_t)(b*KC_ + k)*CC_;
  const float* wr = wij_w + (size_t)k*KX_;
  float acc = 0.f;
  for (int c = lane; c < CC_; c += 64) acc += cr[c] * wr[c];
  const float* sr = s_i + (size_t)b*DH_;
  const float* wsr = wr + CC_;
  #pragma unroll
  for (int j = 0; j < 8; ++j) { int h = lane + j*64; acc += sr[h] * wsr[h]; }
  #pragma unroll
  for (int m = 32; m; m >>= 1) acc += __shfl_xor(acc, m, 64);
  if (lane == 0) ep[gw] = tanhf_fast(acc + wij_b[k]);
}

__global__ void k_cnn_fin(const float* __restrict__ ep, const float* __restrict__ CNNs,
                          float* __restrict__ cp) {
  __shared__ float red[1024];
  __shared__ float apl[B_*KC_];
  int tid = threadIdx.x;
  red[tid] = (tid < B_*KC_) ? ep[tid] : 0.f;
  __syncthreads();
  for (int off = 512; off > 0; off >>= 1) {
    if (tid < off) red[tid] += red[tid + off];
    __syncthreads();
  }
  float S = red[0];
  if (tid < B_*KC_) apl[tid] = __expf(ep[tid]) / S;   // ref: exp(ep)/sum(ep), GLOBAL sum
  __syncthreads();
  for (int idx = tid; idx < B_*CC_; idx += blockDim.x) {
    int b = idx / CC_, c = idx % CC_;
    float acc = 0.f;
    #pragma unroll
    for (int k = 0; k < KC_; ++k)
      acc += apl[b*KC_ + k] * CNNs[(size_t)(b*KC_ + k)*CC_ + c];
    cp[idx] = acc;
  }
}

// ---- Wih fp32 -> bf16 [2048][640], rows reordered nr = dh*4+gate ----
__global__ void k_cvtW(const float* __restrict__ Wih, unsigned short* __restrict__ Wr) {
  int id = blockIdx.x * 256 + threadIdx.x;    // 2048*80
  int nr = id / 80, c8 = (id % 80) * 8;
  int gate = nr & 3, dh = nr >> 2;
  const float* src = Wih + (size_t)(gate*DH_ + dh)*KX_;
  unsigned short o[8];
  #pragma unroll
  for (int j = 0; j < 8; ++j) {
    int col = c8 + j;
    o[j] = (col < KX_) ? f2bf(src[col]) : 0;
  }
  *(uint4*)(Wr + (size_t)nr*KP_ + c8) = *(uint4*)o;
}

// ---- LSTM [b][t][e] fp32 -> LT [b][e][t] bf16 ----
__global__ __launch_bounds__(256) void k_ltrans(const float* __restrict__ LSTM,
                                                unsigned short* __restrict__ LT) {
  int e0 = blockIdx.x * 64, t0 = blockIdx.y * 64, b = blockIdx.z;
  __shared__ float tile[64][65];
  int tid = threadIdx.x;
  int tt = tid >> 2, c16 = (tid & 3) * 16;
  const float4* src = (const float4*)(LSTM + ((size_t)b*TE_ + t0 + tt)*EH_ + e0 + c16);
  float4 v0 = src[0], v1 = src[1], v2 = src[2], v3 = src[3];
  *(float4*)&tile[tt][c16]    = v0;
  *(float4*)&tile[tt][c16+4]  = v1;
  *(float4*)&tile[tt][c16+8]  = v2;
  *(float4*)&tile[tt][c16+12] = v3;
  __syncthreads();
  int e = tid >> 2, t16 = (tid & 3) * 16;
  unsigned short o[16];
  #pragma unroll
  for (int j = 0; j < 16; ++j) o[j] = f2bf(tile[t16+j][e]);
  unsigned short* dst = LT + ((size_t)b*EH_ + e0 + e)*TE_ + t0 + t16;
  *(uint4*)dst     = *(uint4*)&o[0];
  *(uint4*)(dst+8) = *(uint4*)&o[8];
}

// ---------- phase 1: banded logits MFMA band-GEMM ----------
#define BMM_M 64
#define LDA_  40
#define LDB_  40
#define OTS_  132   // tile row stride in floats
__global__ __launch_bounds__(256) void k_bandmm(const float* __restrict__ LSTM,
                                                const float* __restrict__ phi,
                                                const float* __restrict__ Ua_w,
                                                const float* __restrict__ Ua_b,
                                                const float* __restrict__ va_w,
                                                const float* __restrict__ va_b,
                                                const float* __restrict__ wa,
                                                float* __restrict__ ET) {
  int t0 = blockIdx.x * BMM_M;   // 8 tiles
  int b  = blockIdx.y;           // 128
  int s_base = 321 - t0;
  __shared__ __align__(16) char smem[BMM_M * OTS_ * 4];   // 33.8 KB
  short* sA = (short*)smem;                 // [64][40]
  short* sB = (short*)(smem + BMM_M*LDA_*2);// [192][40]
  int tid = threadIdx.x;
  int wave = tid >> 6, lane = tid & 63;
  int quad = lane >> 4, l16 = lane & 15;

  f32x4 acc[4][3];
  #pragma unroll
  for (int m = 0; m < 4; ++m)
    #pragma unroll
    for (int n = 0; n < 3; ++n)
      acc[m][n] = (f32x4){0.f, 0.f, 0.f, 0.f};

  int arow = tid >> 2;             // 0..63
  int ach  = (tid & 3) * 8;        // shorts
  int aq   = ach >> 2;             // float4 units

  const float4* baseL = (const float4*)(LSTM + ((size_t)b*TE_ + t0 + arow)*EH_);
  const float4* baseP = (const float4*)(phi + (size_t)(t0 + arow)*EH_);
  const float4* baseU[3];
  int brow[3], bch[3];
  #pragma unroll
  for (int c = 0; c < 3; ++c) {
    int idx = c*256 + tid;
    brow[c] = idx >> 2;
    bch[c]  = (idx & 3) * 8;
    int s = s_base + brow[c];
    int sc = s < 0 ? 0 : (s > 511 ? 511 : s);
    baseU[c] = (const float4*)(Ua_w + (size_t)sc*EH_ + bch[c]);
  }

  float4 l0 = baseL[aq], l1 = baseL[aq+1], p0 = baseP[aq], p1 = baseP[aq+1];
  float4 u0[3], u1[3];
  #pragma unroll
  for (int c = 0; c < 3; ++c) { u0[c] = baseU[c][0]; u1[c] = baseU[c][1]; }

  for (int k0 = 0; k0 < EH_; k0 += 32) {
    unsigned short at[8];
    at[0]=f2bf(l0.x*p0.x); at[1]=f2bf(l0.y*p0.y); at[2]=f2bf(l0.z*p0.z); at[3]=f2bf(l0.w*p0.w);
    at[4]=f2bf(l1.x*p1.x); at[5]=f2bf(l1.y*p1.y); at[6]=f2bf(l1.z*p1.z); at[7]=f2bf(l1.w*p1.w);
    unsigned short bt[3][8];
    #pragma unroll
    for (int c = 0; c < 3; ++c) {
      bt[c][0]=f2bf(u0[c].x); bt[c][1]=f2bf(u0[c].y); bt[c][2]=f2bf(u0[c].z); bt[c][3]=f2bf(u0[c].w);
      bt[c][4]=f2bf(u1[c].x); bt[c][5]=f2bf(u1[c].y); bt[c][6]=f2bf(u1[c].z); bt[c][7]=f2bf(u1[c].w);
    }
    if (k0 + 32 < EH_) {                       // prefetch next chunk
      int q = (k0 + 32) >> 2;
      l0 = baseL[q+aq]; l1 = baseL[q+aq+1]; p0 = baseP[q+aq]; p1 = baseP[q+aq+1];
      #pragma unroll
      for (int c = 0; c < 3; ++c) { u0[c] = baseU[c][q]; u1[c] = baseU[c][q+1]; }
    }
    __syncthreads();
    *(uint4*)&sA[arow*LDA_ + ach] = *(uint4*)at;
    #pragma unroll
    for (int c = 0; c < 3; ++c)
      *(uint4*)&sB[brow[c]*LDB_ + bch[c]] = *(uint4*)bt[c];
    __syncthreads();
    bf16x8 bfr[3];
    #pragma unroll
    for (int n = 0; n < 3; ++n)
      bfr[n] = *(const bf16x8*)&sB[(l16 + (wave*3 + n)*16)*LDB_ + quad*8];
    #pragma unroll
    for (int m = 0; m < 4; ++m) {
      bf16x8 af = *(const bf16x8*)&sA[(l16 + m*16)*LDA_ + quad*8];
      #pragma unroll
      for (int n = 0; n < 3; ++n)
        acc[m][n] = __builtin_amdgcn_mfma_f32_16x16x32_bf16(af, bfr[n], acc[m][n], 0, 0, 0);
    }
  }

  __syncthreads();                 // sA/sB dead -> reuse smem as output tile
  float* tileO = (float*)smem;     // [64][OTS_]
  float vb = va_b[0];
  #pragma unroll
  for (int n = 0; n < 3; ++n) {
    int s = s_base + wave*48 + n*16 + l16;
    float ub = (s >= 0 && s < TE_) ? Ua_b[s] : 0.f;
    float vw = (s >= 0 && s < TE_) ? va_w[TD_ + s] : 0.f;
    #pragma unroll
    for (int m = 0; m < 4; ++m) {
      #pragma unroll
      for (int r = 0; r < 4; ++r) {
        int tl = m*16 + quad*4 + r;        // t - t0
        int i = s + t0 + tl - 384;
        if (i >= 0 && i < TD_) {
          float val;
          if (s >= 0) val = tanhf_fast(acc[m][n][r] + ub) * vw + vb;
          else        val = wa[b*TD_ + s + 128] + vb;
          tileO[tl*OTS_ + i] = val;
        }
      }
    }
  }
  __syncthreads();
  // cooperative aligned store: 64 rows x 128 floats, every line written once
  {
    int rsub = tid >> 5, c4 = (tid & 31) * 4;
    #pragma unroll
    for (int p = 0; p < 8; ++p) {
      int row = p*8 + rsub;
      float4 v = *(const float4*)&tileO[row*OTS_ + c4];
      *(float4*)(ET + ((size_t)b*TE_ + t0 + row)*TD_ + c4) = v;
    }
  }
}

// ---------------- phase 2: softmax stats over t ----------------
__global__ __launch_bounds__(256) void k_stats(const float* __restrict__ ET,
                                               float* __restrict__ stat) {
  int i0 = blockIdx.x * 64, b = blockIdx.y;
  __shared__ float red[4][64], smax[64];
  int tid = threadIdx.x;
  int q = tid >> 6, il = tid & 63;
  const float* col = ET + (size_t)b*TE_*TD_ + i0 + il;
  float m = -1e30f;
  for (int t = q*128; t < q*128 + 128; ++t) m = fmaxf(m, col[(size_t)t*TD_]);
  red[q][il] = m;
  __syncthreads();
  if (tid < 64) {
    float mm = fmaxf(fmaxf(red[0][tid], red[1][tid]), fmaxf(red[2][tid], red[3][tid]));
    smax[tid] = mm;
  }
  __syncthreads();
  float mm = smax[il];
  float s = 0.f;
  for (int t = q*128; t < q*128 + 128; ++t) s += __expf(col[(size_t)t*TD_] - mm);
  __syncthreads();
  red[q][il] = s;
  __syncthreads();
  if (tid < 64) {
    float ss = red[0][tid] + red[1][tid] + red[2][tid] + red[3][tid];
    stat[b*TD_ + i0 + tid] = smax[tid];
    stat[(size_t)B_*TD_ + b*TD_ + i0 + tid] = 1.f/ss;
  }
}

// ---- ET [b][t][i] + stats -> P [b][i][t] bf16 (softmax applied, transposed) ----
__global__ __launch_bounds__(256) void k_trP(const float* __restrict__ ET,
                                             const float* __restrict__ stat,
                                             unsigned short* __restrict__ P) {
  int t0 = blockIdx.x * 64, i0 = blockIdx.y * 64, b = blockIdx.z;
  __shared__ float tile[64][65];
  __shared__ float smL[64], svL[64];
  int tid = threadIdx.x;
  if (tid < 64) {
    smL[tid] = stat[b*TD_ + i0 + tid];
    svL[tid] = stat[(size_t)B_*TD_ + b*TD_ + i0 + tid];
  }
  int tt = tid >> 2, c16 = (tid & 3) * 16;
  const float4* src = (const float4*)(ET + ((size_t)b*TE_ + t0 + tt)*TD_ + i0 + c16);
  float4 v[4]; v[0] = src[0]; v[1] = src[1]; v[2] = src[2]; v[3] = src[3];
  __syncthreads();
  const float* vf = (const float*)v;
  #pragma unroll
  for (int j = 0; j < 16; ++j)
    tile[tt][c16+j] = __expf(vf[j] - smL[c16+j]) * svL[c16+j];
  __syncthreads();
  int i = tid >> 2, t16 = (tid & 3) * 16;
  unsigned short o[16];
  #pragma unroll
  for (int j = 0; j < 16; ++j) o[j] = f2bf(tile[t16+j][i]);
  unsigned short* dst = P + ((size_t)b*TD_ + i0 + i)*TE_ + t0 + t16;
  *(uint4*)dst     = *(uint4*)&o[0];
  *(uint4*)(dst+8) = *(uint4*)&o[8];
}

// ---- fill X[:,512:640] from cp (bf16), zero pad ----
__global__ void k_cp_fill(const float* __restrict__ cp, unsigned short* __restrict__ X) {
  int id = blockIdx.x * 256 + threadIdx.x;  // 16384*16
  int m = id >> 4, c8 = (id & 15) * 8;
  int b = m >> 7;
  unsigned short o[8];
  #pragma unroll
  for (int j = 0; j < 8; ++j) {
    int c = c8 + j;
    o[j] = (c < CC_) ? f2bf(cp[b*CC_ + c]) : 0;
  }
  *(uint4*)(X + (size_t)m*KP_ + EH_ + c8) = *(uint4*)o;
}

// ------ phase 3 (MFMA, BK=32): X[b*128+i][e] = sum_t P[b][i][t]*LT[b][e][t] ------
#define CI_LD 40
__global__ __launch_bounds__(256) void k_ci_mm(const unsigned short* __restrict__ P,
                                               const unsigned short* __restrict__ LT,
                                               unsigned short* __restrict__ X) {
  int b = blockIdx.x, e0 = blockIdx.y * 128;
  __shared__ short sA[128 * CI_LD];
  __shared__ short sB[128 * CI_LD];
  int tid = threadIdx.x;
  int wave = tid >> 6, lane = tid & 63, quad = lane >> 4, l16 = lane & 15;
  int wm = wave >> 1, wn = wave & 1;
  int row = tid >> 1, ho = (tid & 1) * 16;

  const unsigned short* pa = P + ((size_t)b*TD_ + row)*TE_ + ho;
  const unsigned short* pb = LT + ((size_t)b*EH_ + e0 + row)*TE_ + ho;

  f32x4 acc[4][4];
  #pragma unroll
  for (int m = 0; m < 4; ++m)
    #pragma unroll
    for (int n = 0; n < 4; ++n)
      acc[m][n] = (f32x4){0.f, 0.f, 0.f, 0.f};

  uint4 a0 = *(const uint4*)pa, a1 = *(const uint4*)(pa + 8);
  uint4 b0 = *(const uint4*)pb, b1 = *(const uint4*)(pb + 8);

  for (int k0 = 0; k0 < TE_; k0 += 32) {
    uint4 na0, na1, nb0, nb1;
    if (k0 + 32 < TE_) {
      na0 = *(const uint4*)(pa + k0 + 32); na1 = *(const uint4*)(pa + k0 + 40);
      nb0 = *(const uint4*)(pb + k0 + 32); nb1 = *(const uint4*)(pb + k0 + 40);
    }
    __syncthreads();
    *(uint4*)&sA[row*CI_LD + ho]     = a0;
    *(uint4*)&sA[row*CI_LD + ho + 8] = a1;
    *(uint4*)&sB[row*CI_LD + ho]     = b0;
    *(uint4*)&sB[row*CI_LD + ho + 8] = b1;
    __syncthreads();
    bf16x8 bfr[4];
    #pragma unroll
    for (int n = 0; n < 4; ++n)
      bfr[n] = *(const bf16x8*)&sB[(wn*64 + n*16 + l16)*CI_LD + quad*8];
    #pragma unroll
    for (int m = 0; m < 4; ++m) {
      bf16x8 af = *(const bf16x8*)&sA[(wm*64 + m*16 + l16)*CI_LD + quad*8];
      #pragma unroll
      for (int n = 0; n < 4; ++n)
        acc[m][n] = __builtin_amdgcn_mfma_f32_16x16x32_bf16(af, bfr[n], acc[m][n], 0, 0, 0);
    }
    a0 = na0; a1 = na1; b0 = nb0; b1 = nb1;
  }

  #pragma unroll
  for (int m = 0; m < 4; ++m) {
    int i = wm*64 + m*16 + quad*4;
    #pragma unroll
    for (int n = 0; n < 4; ++n) {
      int e = e0 + wn*64 + n*16 + l16;
      unsigned short* xp = X + ((size_t)b*TD_ + i)*KP_ + e;
      #pragma unroll
      for (int r = 0; r < 4; ++r)
        xp[(size_t)r*KP_] = f2bf(acc[m][n][r]);
    }
  }
}

// -- phase 4: 256x256x(BK=64) deep-phase gates GEMM + fused LSTM cell --
__global__ __launch_bounds__(512, 2) void k_gates8(const unsigned short* __restrict__ Wr,
                                                   const unsigned short* __restrict__ X,
                                                   const float* __restrict__ hpre,
                                                   const float* __restrict__ m_i,
                                                   float* __restrict__ out) {
  __shared__ short lds[4 * 256 * 64];       // 128 KiB: [buf][A|B][256][64]
  const int g0  = blockIdx.x * 256;
  const int mi0 = blockIdx.y * 256;
  const int tid  = threadIdx.x;
  const int wave = tid >> 6, lane = tid & 63;
  const int l16 = lane & 15, quad = lane >> 4;
  const int wr = wave >> 2, wc = wave & 3;  // 2 x 4 wave grid, per-wave 128g x 64mi

  // staging geometry (fixed per thread)
  const int srow8 = lane >> 3;              // row within the wave's 8-row chunk
  const int sch   = (lane & 7) ^ srow8;     // pre-swizzled source chunk
  const unsigned short* gA = Wr + (size_t)(g0  + wave*8 + srow8) * KP_ + sch*8;
  const unsigned short* gB = X  + (size_t)(mi0 + wave*8 + srow8) * KP_ + sch*8;
  short* lA0 = lds;
  short* lB0 = lds + 16384;
  short* lA1 = lds + 32768;
  short* lB1 = lds + 49152;

  f32x4 acc[8][4];
  #pragma unroll
  for (int m = 0; m < 8; ++m)
    #pragma unroll
    for (int n = 0; n < 4; ++n) acc[m][n] = (f32x4){0.f, 0.f, 0.f, 0.f};

  auto stage = [&](int kt, int bf) {
    short* la = bf ? lA1 : lA0;
    short* lb = bf ? lB1 : lB0;
    const unsigned short* ga = gA + kt*64;
    const unsigned short* gb = gB + kt*64;
    #pragma unroll
    for (int r = 0; r < 4; ++r) {           // rounds: rows r*64 + wave*8 + srow8
      gload16(ga + (size_t)r*64*KP_, la + (r*8 + wave)*512);
      gload16(gb + (size_t)r*64*KP_, lb + (r*8 + wave)*512);
    }
  };

  stage(0, 0);
  __syncthreads();                           // drains vmcnt: tile 0 resident

  const int x7 = l16 & 7;
  for (int kt = 0; kt < GNT; ++kt) {
    const int cur = kt & 1;
    if (kt + 1 < GNT) stage(kt + 1, cur ^ 1);   // prefetch, 4 phases of cover
    const short* la = cur ? lA1 : lA0;
    const short* lb = cur ? lB1 : lB0;
    #pragma unroll
    for (int ks = 0; ks < 2; ++ks) {
      const int ck = ((((ks << 2) | quad) ^ x7) << 3);   // swizzled col (shorts)
      bf16x8 bv[4];
      #pragma unroll
      for (int n = 0; n < 4; ++n)
        bv[n] = *(const bf16x8*)&lb[(wc*64 + n*16 + l16)*64 + ck];
      #pragma unroll
      for (int qm = 0; qm < 2; ++qm) {
        bf16x8 av[4];
        #pragma unroll
        for (int m = 0; m < 4; ++m)
          av[m] = *(const bf16x8*)&la[(wr*128 + qm*64 + m*16 + l16)*64 + ck];
        __builtin_amdgcn_s_setprio(1);
        #pragma unroll
        for (int m = 0; m < 4; ++m)
          #pragma unroll
          for (int n = 0; n < 4; ++n)
            acc[qm*4 + m][n] = __builtin_amdgcn_mfma_f32_16x16x32_bf16(av[m], bv[n], acc[qm*4 + m][n], 0, 0, 0);
        __builtin_amdgcn_s_setprio(0);
      }
    }
    __syncthreads();   // implicit vmcnt(0): tile kt+1 landed; frees buf cur
  }

  // epilogue: lane regs r=0..3 are (ig,fg,gg,og) of one dh; b uniform per wave
  const int bb = (mi0 >> 7) + (wc >> 1);
  const float* hp = hpre + (size_t)bb * G_;
  #pragma unroll
  for (int M = 0; M < 8; ++M) {
    const int dh = (g0 >> 2) + wr*32 + M*4 + quad;
    float h0 = hp[dh], h1 = hp[DH_ + dh], h2 = hp[2*DH_ + dh], h3 = hp[3*DH_ + dh];
    float miv = m_i[(size_t)bb*DH_ + dh];
    #pragma unroll
    for (int n = 0; n < 4; ++n) {
      int mi = mi0 + wc*64 + n*16 + l16;
      float ig = acc[M][n][0] + h0;
      float fg = acc[M][n][1] + h1;
      float gg = acc[M][n][2] + h2;
      float og = acc[M][n][3] + h3;
      float c  = sigm(fg)*miv + sigm(ig)*tanhf_fast(gg);
      float h  = sigm(og)*tanhf_fast(c);
      out[(size_t)mi*DH_ + dh] = h;
    }
  }
}

extern "C" void kernel_launch(void* const* d_in, const int* in_sizes, int n_in,
                              void* d_out, int out_size, void* d_ws, size_t ws_size,
                              hipStream_t stream) {
  (void)in_sizes; (void)n_in; (void)out_size; (void)ws_size;
  const float* LSTM  = (const float*)d_in[0];
  const float* CNNs  = (const float*)d_in[1];
  const float* Wa_w  = (const float*)d_in[2];
  const float* Wa_b  = (const float*)d_in[3];
  const float* Ua_w  = (const float*)d_in[4];
  const float* Ua_b  = (const float*)d_in[5];
  const float* va_w  = (const float*)d_in[6];
  const float* va_b  = (const float*)d_in[7];
  const float* phi_w = (const float*)d_in[8];
  const float* phi_b = (const float*)d_in[9];
  const float* Wih   = (const float*)d_in[10];
  const float* Whh   = (const float*)d_in[11];
  const float* bih   = (const float*)d_in[12];
  const float* bhh   = (const float*)d_in[13];
  const float* wij_w = (const float*)d_in[14];
  const float* wij_b = (const float*)d_in[15];
  const float* s_i   = (const float*)d_in[16];
  const float* m_i   = (const float*)d_in[17];
  float* out = (float*)d_out;
  char* ws = (char*)d_ws;

  float* phi  = (float*)(ws + OFF_PHI);
  float* wa   = (float*)(ws + OFF_WA);
  float* hpre = (float*)(ws + OFF_HPRE);
  float* ep   = (float*)(ws + OFF_EP);
  float* cp   = (float*)(ws + OFF_CP);
  float* stat = (float*)(ws + OFF_STAT);
  float* ET   = (float*)(ws + OFF_ET);
  unsigned short* X  = (unsigned short*)(ws + OFF_ET);   // aliases ET (dead after k_trP)
  unsigned short* P  = (unsigned short*)(ws + OFF_P);
  unsigned short* LT = (unsigned short*)(ws + OFF_LT);
  unsigned short* Wr = (unsigned short*)(ws + OFF_WR);
  float* phiT        = (float*)(ws + OFF_PT);            // aliases P region (pre-trP)
  float* sums        = (float*)(ws + OFF_SUM);           // aliases P region
  float* WhhT        = (float*)(ws + OFF_WT);            // aliases P region (pre-trP)
  float* WaT         = (float*)(ws + OFF_WAT);           // aliases P region (pre-trP)

  k_tr      <<<dim3(8,8),      dim3(256),  0, stream>>>(phi_w, phiT, 512, 512);
  k_tr      <<<dim3(32,8),     dim3(256),  0, stream>>>(Whh, WhhT, 2048, 512);
  k_tr      <<<dim3(2,8),      dim3(256),  0, stream>>>(Wa_w, WaT, 128, 512);
  k_phiA    <<<dim3(2,8),      dim3(256),  0, stream>>>(phiT, phi, sums);
  k_phiB    <<<dim3(2,8),      dim3(256),  0, stream>>>(sums, phi_b, phi);
  k_wa2     <<<dim3(32),       dim3(256),  0, stream>>>(s_i, WaT, Wa_b, va_w, wa);
  k_hpre2   <<<dim3(8,64),     dim3(64),   0, stream>>>(s_i, WhhT, bih, bhh, hpre);
  k_ep      <<<dim3(224),      dim3(256),  0, stream>>>(CNNs, wij_w, wij_b, s_i, ep);
  k_cnn_fin <<<dim3(1),        dim3(1024), 0, stream>>>(ep, CNNs, cp);
  k_cvtW    <<<dim3(640),      dim3(256),  0, stream>>>(Wih, Wr);
  k_ltrans  <<<dim3(8,8,128),  dim3(256),  0, stream>>>(LSTM, LT);
  k_bandmm  <<<dim3(8,128),    dim3(256),  0, stream>>>(LSTM, phi, Ua_w, Ua_b, va_w, va_b, wa, ET);
  k_stats   <<<dim3(2,128),    dim3(256),  0, stream>>>(ET, stat);
  k_trP     <<<dim3(8,2,128),  dim3(256),  0, stream>>>(ET, stat, P);
  k_cp_fill <<<dim3(1024),     dim3(256),  0, stream>>>(cp, X);
  k_ci_mm   <<<dim3(128,4),    dim3(256),  0, stream>>>(P, LT, X);
  k_gates8  <<<dim3(8,64),     dim3(512),  0, stream>>>(Wr, X, hpre, m_i, out);
}

// Round 6
// 489.045 us; speedup vs baseline: 1.3303x; 1.0891x over previous
//
#include <hip/hip_runtime.h>
#include <hip/hip_bf16.h>

#define B_   128
#define TE_  512
#define TD_  128
#define EH_  512
#define DH_  512
#define KC_  7
#define CC_  105
#define G_   2048   // 4*DH
#define KX_  617    // EH + CC
#define KP_  640    // padded K for gates GEMM
#define GNT  10     // KP_/64 K-tiles for gates GEMM

typedef __attribute__((ext_vector_type(8))) short bf16x8;
typedef __attribute__((ext_vector_type(4))) float f32x4;

__device__ __forceinline__ float sigm(float x){ return 1.f/(1.f + __expf(-x)); }
__device__ __forceinline__ float tanhf_fast(float x){
  float e = __expf(2.f*x);
  return 1.f - 2.f/(e + 1.f);
}

// fp32 -> bf16 (RNE)
__device__ __forceinline__ unsigned short f2bf(float f){
  unsigned int u = __float_as_uint(f);
  unsigned int r = (u + 0x7fffu + ((u >> 16) & 1u)) >> 16;
  return (unsigned short)r;
}

// async global->LDS, 16B per lane; LDS dest = wave-uniform base + lane*16
typedef __attribute__((address_space(3))) unsigned int lds_u32_t;
typedef __attribute__((address_space(1))) const unsigned int glb_u32_t;
__device__ __forceinline__ void gload16(const void* g, void* l) {
  __builtin_amdgcn_global_load_lds((glb_u32_t*)g, (lds_u32_t*)l, 16, 0, 0);
}

// ---------------- workspace layout (bytes) ----------------
static const size_t OFF_PHI  = 0;                                         // 1 MB
static const size_t OFF_WA   = OFF_PHI  + (size_t)TE_*EH_*4;              // 64 KB
static const size_t OFF_HPRE = OFF_WA   + (size_t)B_*TD_*4;               // 1 MB
static const size_t OFF_EP   = OFF_HPRE + (size_t)B_*G_*4;                // 4 KB (ep 896 f + epsum @1000)
static const size_t OFF_CP   = OFF_EP   + 4096;                           // 53.8 KB (unused now)
static const size_t OFF_ET   = ((OFF_CP + (size_t)B_*CC_*4 + 255)/256)*256; // 33.5 MB fp32 [b][t][i]; X bf16 aliases
static const size_t OFF_STAT = OFF_ET + (size_t)B_*TE_*TD_*4;             // 128 KB (unused now)
static const size_t OFF_P    = ((OFF_STAT + (size_t)2*B_*TD_*4 + 255)/256)*256; // 16.7 MB bf16
static const size_t OFF_LT   = OFF_P  + (size_t)B_*TD_*TE_*2;             // 67 MB bf16
static const size_t OFF_WR   = OFF_LT + (size_t)B_*TE_*EH_*2;             // 2.6 MB bf16
// scratch aliases inside P region (all consumed before k_smx writes P):
static const size_t OFF_PT   = OFF_P;                                     // 1 MB fp32 phi_w^T
static const size_t OFF_SUM  = OFF_PT + (size_t)TE_*EH_*4;                // 16 KB scan sums
static const size_t OFF_WT   = OFF_P + (size_t)2*1024*1024;               // 4 MB Whh^T fp32
static const size_t OFF_WAT  = OFF_P + (size_t)6*1024*1024;               // 256 KB Wa_w^T fp32

// ---- generic fp32 transpose: src[R][C] -> dst[C][R], 64x64 tiles ----
__global__ __launch_bounds__(256) void k_tr(const float* __restrict__ src,
                                            float* __restrict__ dst, int R, int C) {
  int r0 = blockIdx.x * 64, c0 = blockIdx.y * 64;
  __shared__ float tile[64][65];
  int tid = threadIdx.x;
  int r = tid >> 2, c16 = (tid & 3) * 16;
  const float4* s4 = (const float4*)(src + (size_t)(r0 + r)*C + c0 + c16);
  float4 v0 = s4[0], v1 = s4[1], v2 = s4[2], v3 = s4[3];
  *(float4*)&tile[r][c16]    = v0;
  *(float4*)&tile[r][c16+4]  = v1;
  *(float4*)&tile[r][c16+8]  = v2;
  *(float4*)&tile[r][c16+12] = v3;
  __syncthreads();
  float o[16];
  #pragma unroll
  for (int j = 0; j < 16; ++j) o[j] = tile[c16+j][r];
  float* d = dst + (size_t)(c0 + r)*R + r0 + c16;
  *(float4*)d      = *(float4*)&o[0];
  *(float4*)(d+4)  = *(float4*)&o[4];
  *(float4*)(d+8)  = *(float4*)&o[8];
  *(float4*)(d+12) = *(float4*)&o[12];
}

// ---- split exclusive scan over t ----
__global__ void k_phiA(const float* __restrict__ phiT, float* __restrict__ phi,
                       float* __restrict__ sums) {
  int e = blockIdx.x * 256 + threadIdx.x;   // 512
  int z = blockIdx.y;                        // 8 chunks of 64 t
  float acc = 0.f;
  for (int t = z*64; t < z*64 + 64; ++t) {
    phi[(size_t)t*EH_ + e] = acc;
    acc += phiT[(size_t)t*EH_ + e];
  }
  sums[z*EH_ + e] = acc;
}
__global__ void k_phiB(const float* __restrict__ sums, const float* __restrict__ phi_b,
                       float* __restrict__ phi) {
  int e = blockIdx.x * 256 + threadIdx.x;
  int z = blockIdx.y;
  float off = phi_b[e];
  for (int zz = 0; zz < z; ++zz) off += sums[zz*EH_ + e];
  for (int t = z*64; t < z*64 + 64; ++t)
    phi[(size_t)t*EH_ + e] += off;
}

// ---- wa[b][d] = tanh(s_i[b].Wa_w[d] + Wa_b[d]) * va_w[d], coalesced via WaT ----
__global__ __launch_bounds__(256) void k_wa2(const float* __restrict__ s_i,
                                             const float* __restrict__ WaT,
                                             const float* __restrict__ Wa_b,
                                             const float* __restrict__ va_w,
                                             float* __restrict__ wa) {
  int lane = threadIdx.x & 63, wv = threadIdx.x >> 6;
  int b = blockIdx.x * 4 + wv;               // 32 blocks x 4 waves = 128 b
  int d0 = lane * 2;
  const float2* w = (const float2*)WaT + lane;   // row stride 64 float2
  const float* s = s_i + (size_t)b*DH_;
  float ax = 0.f, ay = 0.f;
  #pragma unroll 8
  for (int k = 0; k < DH_; ++k) {
    float2 wv2 = w[(size_t)k*64];
    float x = s[k];
    ax += wv2.x * x; ay += wv2.y * x;
  }
  wa[b*TD_ + d0]     = tanhf_fast(ax + Wa_b[d0])     * va_w[d0];
  wa[b*TD_ + d0 + 1] = tanhf_fast(ay + Wa_b[d0 + 1]) * va_w[d0 + 1];
}

// ---- hpre[b][g] = bih[g]+bhh[g] + s_i[b].Whh[g], via WhhT ----
__global__ __launch_bounds__(256) void k_hpre2(const float* __restrict__ s_i,
                                               const float* __restrict__ WhhT,
                                               const float* __restrict__ bih,
                                               const float* __restrict__ bhh,
                                               float* __restrict__ hpre) {
  int gq = blockIdx.x * 256 + threadIdx.x;   // 0..511 float4-group of g
  int b  = blockIdx.y;                       // 128
  const float4* w = (const float4*)WhhT + gq;    // row stride 512 float4
  const float* s = s_i + (size_t)b*DH_;
  float4 a = {0.f,0.f,0.f,0.f};
  #pragma unroll 8
  for (int k = 0; k < DH_; ++k) {
    float4 wv = w[(size_t)k*512];
    float x = s[k];
    a.x += wv.x*x; a.y += wv.y*x; a.z += wv.z*x; a.w += wv.w*x;
  }
  int g = gq * 4;
  float4 bi = *(const float4*)(bih + g);
  float4 bh = *(const float4*)(bhh + g);
  float4 o;
  o.x = a.x + bi.x + bh.x; o.y = a.y + bi.y + bh.y;
  o.z = a.z + bi.z + bh.z; o.w = a.w + bi.w + bh.w;
  *(float4*)(hpre + (size_t)b*G_ + g) = o;
}

// ---- ep: one wave per (b,k) ----
__global__ __launch_bounds__(256) void k_ep(const float* __restrict__ CNNs,
                                            const float* __restrict__ wij_w,
                                            const float* __restrict__ wij_b,
                                            const float* __restrict__ s_i,
                                            float* __restrict__ ep) {
  int gw = blockIdx.x * 4 + (threadIdx.x >> 6);
  int lane = threadIdx.x & 63;
  if (gw >= B_*KC_) return;
  int b = gw / KC_, k = gw % KC_;
  const float* cr = CNNs + (size_t)(b*KC_ + k)*CC_;
  const float* wr = wij_w + (size_t)k*KX_;
  float acc = 0.f;
  for (int c = lane; c < CC_; c += 64) acc += cr[c] * wr[c];
  const float* sr = s_i + (size_t)b*DH_;
  const float* wsr = wr + CC_;
  #pragma unroll
  for (int j = 0; j < 8; ++j) { int h = lane + j*64; acc += sr[h] * wsr[h]; }
  #pragma unroll
  for (int m = 32; m; m >>= 1) acc += __shfl_xor(acc, m, 64);
  if (lane == 0) ep[gw] = tanhf_fast(acc + wij_b[k]);
}

// ---- global raw-sum of ep (ref: sum(ep), not sum(exp)) ----
__global__ void k_epsum(const float* __restrict__ ep, float* __restrict__ epsum) {
  __shared__ float red[1024];
  int tid = threadIdx.x;
  red[tid] = (tid < B_*KC_) ? ep[tid] : 0.f;
  __syncthreads();
  for (int off = 512; off > 0; off >>= 1) {
    if (tid < off) red[tid] += red[tid + off];
    __syncthreads();
  }
  if (tid == 0) epsum[0] = red[0];
}

// ---- per-b: ap = exp(ep)/S, c_p = ap.CNNs, write X[:,512:640] bf16 directly ----
__global__ __launch_bounds__(128) void k_cp(const float* __restrict__ ep,
                                            const float* __restrict__ epsum,
                                            const float* __restrict__ CNNs,
                                            unsigned short* __restrict__ X) {
  int b = blockIdx.x, c = threadIdx.x;   // 128 threads
  float S = epsum[0];
  float apl[KC_];
  #pragma unroll
  for (int k = 0; k < KC_; ++k) apl[k] = __expf(ep[b*KC_ + k]) / S;
  float acc = 0.f;
  if (c < CC_) {
    #pragma unroll
    for (int k = 0; k < KC_; ++k)
      acc += apl[k] * CNNs[(size_t)(b*KC_ + k)*CC_ + c];
  }
  unsigned short o = (c < CC_) ? f2bf(acc) : 0;
  unsigned short* xb = X + (size_t)b*TD_*KP_ + EH_ + c;
  for (int i = 0; i < TD_; ++i)
    xb[(size_t)i*KP_] = o;
}

// ---- Wih fp32 -> bf16 [2048][640], rows reordered nr = dh*4+gate ----
__global__ void k_cvtW(const float* __restrict__ Wih, unsigned short* __restrict__ Wr) {
  int id = blockIdx.x * 256 + threadIdx.x;    // 2048*80
  int nr = id / 80, c8 = (id % 80) * 8;
  int gate = nr & 3, dh = nr >> 2;
  const float* src = Wih + (size_t)(gate*DH_ + dh)*KX_;
  unsigned short o[8];
  #pragma unroll
  for (int j = 0; j < 8; ++j) {
    int col = c8 + j;
    o[j] = (col < KX_) ? f2bf(src[col]) : 0;
  }
  *(uint4*)(Wr + (size_t)nr*KP_ + c8) = *(uint4*)o;
}

// ---- LSTM [b][t][e] fp32 -> LT [b][e][t] bf16 ----
__global__ __launch_bounds__(256) void k_ltrans(const float* __restrict__ LSTM,
                                                unsigned short* __restrict__ LT) {
  int e0 = blockIdx.x * 64, t0 = blockIdx.y * 64, b = blockIdx.z;
  __shared__ float tile[64][65];
  int tid = threadIdx.x;
  int tt = tid >> 2, c16 = (tid & 3) * 16;
  const float4* src = (const float4*)(LSTM + ((size_t)b*TE_ + t0 + tt)*EH_ + e0 + c16);
  float4 v0 = src[0], v1 = src[1], v2 = src[2], v3 = src[3];
  *(float4*)&tile[tt][c16]    = v0;
  *(float4*)&tile[tt][c16+4]  = v1;
  *(float4*)&tile[tt][c16+8]  = v2;
  *(float4*)&tile[tt][c16+12] = v3;
  __syncthreads();
  int e = tid >> 2, t16 = (tid & 3) * 16;
  unsigned short o[16];
  #pragma unroll
  for (int j = 0; j < 16; ++j) o[j] = f2bf(tile[t16+j][e]);
  unsigned short* dst = LT + ((size_t)b*EH_ + e0 + e)*TE_ + t0 + t16;
  *(uint4*)dst     = *(uint4*)&o[0];
  *(uint4*)(dst+8) = *(uint4*)&o[8];
}

// ---------- phase 1: banded logits MFMA band-GEMM ----------
#define BMM_M 64
#define LDA_  40
#define LDB_  40
#define OTS_  132   // tile row stride in floats
__global__ __launch_bounds__(256) void k_bandmm(const float* __restrict__ LSTM,
                                                const float* __restrict__ phi,
                                                const float* __restrict__ Ua_w,
                                                const float* __restrict__ Ua_b,
                                                const float* __restrict__ va_w,
                                                const float* __restrict__ va_b,
                                                const float* __restrict__ wa,
                                                float* __restrict__ ET) {
  int t0 = blockIdx.x * BMM_M;   // 8 tiles
  int b  = blockIdx.y;           // 128
  int s_base = 321 - t0;
  __shared__ __align__(16) char smem[BMM_M * OTS_ * 4];   // 33.8 KB
  short* sA = (short*)smem;                 // [64][40]
  short* sB = (short*)(smem + BMM_M*LDA_*2);// [192][40]
  int tid = threadIdx.x;
  int wave = tid >> 6, lane = tid & 63;
  int quad = lane >> 4, l16 = lane & 15;

  f32x4 acc[4][3];
  #pragma unroll
  for (int m = 0; m < 4; ++m)
    #pragma unroll
    for (int n = 0; n < 3; ++n)
      acc[m][n] = (f32x4){0.f, 0.f, 0.f, 0.f};

  int arow = tid >> 2;             // 0..63
  int ach  = (tid & 3) * 8;        // shorts
  int aq   = ach >> 2;             // float4 units

  const float4* baseL = (const float4*)(LSTM + ((size_t)b*TE_ + t0 + arow)*EH_);
  const float4* baseP = (const float4*)(phi + (size_t)(t0 + arow)*EH_);
  const float4* baseU[3];
  int brow[3], bch[3];
  #pragma unroll
  for (int c = 0; c < 3; ++c) {
    int idx = c*256 + tid;
    brow[c] = idx >> 2;
    bch[c]  = (idx & 3) * 8;
    int s = s_base + brow[c];
    int sc = s < 0 ? 0 : (s > 511 ? 511 : s);
    baseU[c] = (const float4*)(Ua_w + (size_t)sc*EH_ + bch[c]);
  }

  float4 l0 = baseL[aq], l1 = baseL[aq+1], p0 = baseP[aq], p1 = baseP[aq+1];
  float4 u0[3], u1[3];
  #pragma unroll
  for (int c = 0; c < 3; ++c) { u0[c] = baseU[c][0]; u1[c] = baseU[c][1]; }

  for (int k0 = 0; k0 < EH_; k0 += 32) {
    unsigned short at[8];
    at[0]=f2bf(l0.x*p0.x); at[1]=f2bf(l0.y*p0.y); at[2]=f2bf(l0.z*p0.z); at[3]=f2bf(l0.w*p0.w);
    at[4]=f2bf(l1.x*p1.x); at[5]=f2bf(l1.y*p1.y); at[6]=f2bf(l1.z*p1.z); at[7]=f2bf(l1.w*p1.w);
    unsigned short bt[3][8];
    #pragma unroll
    for (int c = 0; c < 3; ++c) {
      bt[c][0]=f2bf(u0[c].x); bt[c][1]=f2bf(u0[c].y); bt[c][2]=f2bf(u0[c].z); bt[c][3]=f2bf(u0[c].w);
      bt[c][4]=f2bf(u1[c].x); bt[c][5]=f2bf(u1[c].y); bt[c][6]=f2bf(u1[c].z); bt[c][7]=f2bf(u1[c].w);
    }
    if (k0 + 32 < EH_) {                       // prefetch next chunk
      int q = (k0 + 32) >> 2;
      l0 = baseL[q+aq]; l1 = baseL[q+aq+1]; p0 = baseP[q+aq]; p1 = baseP[q+aq+1];
      #pragma unroll
      for (int c = 0; c < 3; ++c) { u0[c] = baseU[c][q]; u1[c] = baseU[c][q+1]; }
    }
    __syncthreads();
    *(uint4*)&sA[arow*LDA_ + ach] = *(uint4*)at;
    #pragma unroll
    for (int c = 0; c < 3; ++c)
      *(uint4*)&sB[brow[c]*LDB_ + bch[c]] = *(uint4*)bt[c];
    __syncthreads();
    bf16x8 bfr[3];
    #pragma unroll
    for (int n = 0; n < 3; ++n)
      bfr[n] = *(const bf16x8*)&sB[(l16 + (wave*3 + n)*16)*LDB_ + quad*8];
    #pragma unroll
    for (int m = 0; m < 4; ++m) {
      bf16x8 af = *(const bf16x8*)&sA[(l16 + m*16)*LDA_ + quad*8];
      #pragma unroll
      for (int n = 0; n < 3; ++n)
        acc[m][n] = __builtin_amdgcn_mfma_f32_16x16x32_bf16(af, bfr[n], acc[m][n], 0, 0, 0);
    }
  }

  __syncthreads();                 // sA/sB dead -> reuse smem as output tile
  float* tileO = (float*)smem;     // [64][OTS_]
  float vb = va_b[0];
  #pragma unroll
  for (int n = 0; n < 3; ++n) {
    int s = s_base + wave*48 + n*16 + l16;
    float ub = (s >= 0 && s < TE_) ? Ua_b[s] : 0.f;
    float vw = (s >= 0 && s < TE_) ? va_w[TD_ + s] : 0.f;
    #pragma unroll
    for (int m = 0; m < 4; ++m) {
      #pragma unroll
      for (int r = 0; r < 4; ++r) {
        int tl = m*16 + quad*4 + r;        // t - t0
        int i = s + t0 + tl - 384;
        if (i >= 0 && i < TD_) {
          float val;
          if (s >= 0) val = tanhf_fast(acc[m][n][r] + ub) * vw + vb;
          else        val = wa[b*TD_ + s + 128] + vb;
          tileO[tl*OTS_ + i] = val;
        }
      }
    }
  }
  __syncthreads();
  // cooperative aligned store: 64 rows x 128 floats, every line written once
  {
    int rsub = tid >> 5, c4 = (tid & 31) * 4;
    #pragma unroll
    for (int p = 0; p < 8; ++p) {
      int row = p*8 + rsub;
      float4 v = *(const float4*)&tileO[row*OTS_ + c4];
      *(float4*)(ET + ((size_t)b*TE_ + t0 + row)*TD_ + c4) = v;
    }
  }
}

// ---- fused softmax: ET [b][t][i] -> P [b][i][t] bf16 (stats + transpose in LDS) ----
#define SMX_LD 65
__global__ __launch_bounds__(512) void k_smx(const float* __restrict__ ET,
                                             unsigned short* __restrict__ P) {
  int i0 = blockIdx.x * 64, b = blockIdx.y;
  __shared__ float tile[TE_][SMX_LD];        // 130 KB
  __shared__ float red[8][64], smax[64], sinv[64];
  int tid = threadIdx.x;

  // load: 4 reps x 128 rows; thread reads 16 consecutive floats of one row
  {
    int r = tid >> 2, c16 = (tid & 3) * 16;
    #pragma unroll
    for (int rep = 0; rep < 4; ++rep) {
      int t = rep*128 + r;
      const float4* s4 = (const float4*)(ET + ((size_t)b*TE_ + t)*TD_ + i0 + c16);
      float4 v0 = s4[0], v1 = s4[1], v2 = s4[2], v3 = s4[3];
      *(float4*)&tile[t][c16]    = v0;
      *(float4*)&tile[t][c16+4]  = v1;
      *(float4*)&tile[t][c16+8]  = v2;
      *(float4*)&tile[t][c16+12] = v3;
    }
  }
  __syncthreads();

  int i = tid & 63, seg = tid >> 6;          // 64 i x 8 segs of 64 t
  // max
  {
    float m = -1e30f;
    for (int t = seg*64; t < seg*64 + 64; ++t) m = fmaxf(m, tile[t][i]);
    red[seg][i] = m;
  }
  __syncthreads();
  if (tid < 64) {
    float m = red[0][tid];
    #pragma unroll
    for (int s = 1; s < 8; ++s) m = fmaxf(m, red[s][tid]);
    smax[tid] = m;
  }
  __syncthreads();
  // exp in place + sum
  {
    float mm = smax[i];
    float s = 0.f;
    for (int t = seg*64; t < seg*64 + 64; ++t) {
      float v = __expf(tile[t][i] - mm);
      tile[t][i] = v;
      s += v;
    }
    red[seg][i] = s;
  }
  __syncthreads();
  if (tid < 64) {
    float s = red[0][tid];
    #pragma unroll
    for (int sg = 1; sg < 8; ++sg) s += red[sg][tid];
    sinv[tid] = 1.f / s;
  }
  __syncthreads();
  // write P[b][i0+i][t]: transpose read (pad-65), coalesced 32B rows
  {
    int tidq = tid & 255, half = tid >> 8;
    int ii = tidq >> 2, t16 = (tidq & 3) * 16;
    float inv = sinv[ii];
    #pragma unroll
    for (int tt = 0; tt < 4; ++tt) {
      int tb = (tt*2 + half) * 64;
      unsigned short o[16];
      #pragma unroll
      for (int j = 0; j < 16; ++j)
        o[j] = f2bf(tile[tb + t16 + j][ii] * inv);
      unsigned short* dst = P + ((size_t)b*TD_ + i0 + ii)*TE_ + tb + t16;
      *(uint4*)dst     = *(uint4*)&o[0];
      *(uint4*)(dst+8) = *(uint4*)&o[8];
    }
  }
}

// ------ phase 3 (MFMA, BK=32): X[b*128+i][e] = sum_t P[b][i][t]*LT[b][e][t] ------
#define CI_LD 40
__global__ __launch_bounds__(256) void k_ci_mm(const unsigned short* __restrict__ P,
                                               const unsigned short* __restrict__ LT,
                                               unsigned short* __restrict__ X) {
  int b = blockIdx.x, e0 = blockIdx.y * 128;
  __shared__ short sA[128 * CI_LD];
  __shared__ short sB[128 * CI_LD];
  int tid = threadIdx.x;
  int wave = tid >> 6, lane = tid & 63, quad = lane >> 4, l16 = lane & 15;
  int wm = wave >> 1, wn = wave & 1;
  int row = tid >> 1, ho = (tid & 1) * 16;

  const unsigned short* pa = P + ((size_t)b*TD_ + row)*TE_ + ho;
  const unsigned short* pb = LT + ((size_t)b*EH_ + e0 + row)*TE_ + ho;

  f32x4 acc[4][4];
  #pragma unroll
  for (int m = 0; m < 4; ++m)
    #pragma unroll
    for (int n = 0; n < 4; ++n)
      acc[m][n] = (f32x4){0.f, 0.f, 0.f, 0.f};

  uint4 a0 = *(const uint4*)pa, a1 = *(const uint4*)(pa + 8);
  uint4 b0 = *(const uint4*)pb, b1 = *(const uint4*)(pb + 8);

  for (int k0 = 0; k0 < TE_; k0 += 32) {
    uint4 na0, na1, nb0, nb1;
    if (k0 + 32 < TE_) {
      na0 = *(const uint4*)(pa + k0 + 32); na1 = *(const uint4*)(pa + k0 + 40);
      nb0 = *(const uint4*)(pb + k0 + 32); nb1 = *(const uint4*)(pb + k0 + 40);
    }
    __syncthreads();
    *(uint4*)&sA[row*CI_LD + ho]     = a0;
    *(uint4*)&sA[row*CI_LD + ho + 8] = a1;
    *(uint4*)&sB[row*CI_LD + ho]     = b0;
    *(uint4*)&sB[row*CI_LD + ho + 8] = b1;
    __syncthreads();
    bf16x8 bfr[4];
    #pragma unroll
    for (int n = 0; n < 4; ++n)
      bfr[n] = *(const bf16x8*)&sB[(wn*64 + n*16 + l16)*CI_LD + quad*8];
    #pragma unroll
    for (int m = 0; m < 4; ++m) {
      bf16x8 af = *(const bf16x8*)&sA[(wm*64 + m*16 + l16)*CI_LD + quad*8];
      #pragma unroll
      for (int n = 0; n < 4; ++n)
        acc[m][n] = __builtin_amdgcn_mfma_f32_16x16x32_bf16(af, bfr[n], acc[m][n], 0, 0, 0);
    }
    a0 = na0; a1 = na1; b0 = nb0; b1 = nb1;
  }

  #pragma unroll
  for (int m = 0; m < 4; ++m) {
    int i = wm*64 + m*16 + quad*4;
    #pragma unroll
    for (int n = 0; n < 4; ++n) {
      int e = e0 + wn*64 + n*16 + l16;
      unsigned short* xp = X + ((size_t)b*TD_ + i)*KP_ + e;
      #pragma unroll
      for (int r = 0; r < 4; ++r)
        xp[(size_t)r*KP_] = f2bf(acc[m][n][r]);
    }
  }
}

// -- phase 4: 256x256x(BK=64) deep-phase gates GEMM + fused LSTM cell --
__global__ __launch_bounds__(512, 2) void k_gates8(const unsigned short* __restrict__ Wr,
                                                   const unsigned short* __restrict__ X,
                                                   const float* __restrict__ hpre,
                                                   const float* __restrict__ m_i,
                                                   float* __restrict__ out) {
  __shared__ short lds[4 * 256 * 64];       // 128 KiB: [buf][A|B][256][64]
  const int g0  = blockIdx.x * 256;
  const int mi0 = blockIdx.y * 256;
  const int tid  = threadIdx.x;
  const int wave = tid >> 6, lane = tid & 63;
  const int l16 = lane & 15, quad = lane >> 4;
  const int wr = wave >> 2, wc = wave & 3;  // 2 x 4 wave grid, per-wave 128g x 64mi

  // staging geometry (fixed per thread)
  const int srow8 = lane >> 3;              // row within the wave's 8-row chunk
  const int sch   = (lane & 7) ^ srow8;     // pre-swizzled source chunk
  const unsigned short* gA = Wr + (size_t)(g0  + wave*8 + srow8) * KP_ + sch*8;
  const unsigned short* gB = X  + (size_t)(mi0 + wave*8 + srow8) * KP_ + sch*8;
  short* lA0 = lds;
  short* lB0 = lds + 16384;
  short* lA1 = lds + 32768;
  short* lB1 = lds + 49152;

  f32x4 acc[8][4];
  #pragma unroll
  for (int m = 0; m < 8; ++m)
    #pragma unroll
    for (int n = 0; n < 4; ++n) acc[m][n] = (f32x4){0.f, 0.f, 0.f, 0.f};

  auto stage = [&](int kt, int bf) {
    short* la = bf ? lA1 : lA0;
    short* lb = bf ? lB1 : lB0;
    const unsigned short* ga = gA + kt*64;
    const unsigned short* gb = gB + kt*64;
    #pragma unroll
    for (int r = 0; r < 4; ++r) {           // rounds: rows r*64 + wave*8 + srow8
      gload16(ga + (size_t)r*64*KP_, la + (r*8 + wave)*512);
      gload16(gb + (size_t)r*64*KP_, lb + (r*8 + wave)*512);
    }
  };

  stage(0, 0);
  __syncthreads();                           // drains vmcnt: tile 0 resident

  const int x7 = l16 & 7;
  for (int kt = 0; kt < GNT; ++kt) {
    const int cur = kt & 1;
    if (kt + 1 < GNT) stage(kt + 1, cur ^ 1);   // prefetch, 4 phases of cover
    const short* la = cur ? lA1 : lA0;
    const short* lb = cur ? lB1 : lB0;
    #pragma unroll
    for (int ks = 0; ks < 2; ++ks) {
      const int ck = ((((ks << 2) | quad) ^ x7) << 3);   // swizzled col (shorts)
      bf16x8 bv[4];
      #pragma unroll
      for (int n = 0; n < 4; ++n)
        bv[n] = *(const bf16x8*)&lb[(wc*64 + n*16 + l16)*64 + ck];
      #pragma unroll
      for (int qm = 0; qm < 2; ++qm) {
        bf16x8 av[4];
        #pragma unroll
        for (int m = 0; m < 4; ++m)
          av[m] = *(const bf16x8*)&la[(wr*128 + qm*64 + m*16 + l16)*64 + ck];
        __builtin_amdgcn_s_setprio(1);
        #pragma unroll
        for (int m = 0; m < 4; ++m)
          #pragma unroll
          for (int n = 0; n < 4; ++n)
            acc[qm*4 + m][n] = __builtin_amdgcn_mfma_f32_16x16x32_bf16(av[m], bv[n], acc[qm*4 + m][n], 0, 0, 0);
        __builtin_amdgcn_s_setprio(0);
      }
    }
    __syncthreads();   // implicit vmcnt(0): tile kt+1 landed; frees buf cur
  }

  // epilogue: lane regs r=0..3 are (ig,fg,gg,og) of one dh; b uniform per wave
  const int bb = (mi0 >> 7) + (wc >> 1);
  const float* hp = hpre + (size_t)bb * G_;
  #pragma unroll
  for (int M = 0; M < 8; ++M) {
    const int dh = (g0 >> 2) + wr*32 + M*4 + quad;
    float h0 = hp[dh], h1 = hp[DH_ + dh], h2 = hp[2*DH_ + dh], h3 = hp[3*DH_ + dh];
    float miv = m_i[(size_t)bb*DH_ + dh];
    #pragma unroll
    for (int n = 0; n < 4; ++n) {
      int mi = mi0 + wc*64 + n*16 + l16;
      float ig = acc[M][n][0] + h0;
      float fg = acc[M][n][1] + h1;
      float gg = acc[M][n][2] + h2;
      float og = acc[M][n][3] + h3;
      float c  = sigm(fg)*miv + sigm(ig)*tanhf_fast(gg);
      float h  = sigm(og)*tanhf_fast(c);
      out[(size_t)mi*DH_ + dh] = h;
    }
  }
}

extern "C" void kernel_launch(void* const* d_in, const int* in_sizes, int n_in,
                              void* d_out, int out_size, void* d_ws, size_t ws_size,
                              hipStream_t stream) {
  (void)in_sizes; (void)n_in; (void)out_size; (void)ws_size;
  const float* LSTM  = (const float*)d_in[0];
  const float* CNNs  = (const float*)d_in[1];
  const float* Wa_w  = (const float*)d_in[2];
  const float* Wa_b  = (const float*)d_in[3];
  const float* Ua_w  = (const float*)d_in[4];
  const float* Ua_b  = (const float*)d_in[5];
  const float* va_w  = (const float*)d_in[6];
  const float* va_b  = (const float*)d_in[7];
  const float* phi_w = (const float*)d_in[8];
  const float* phi_b = (const float*)d_in[9];
  const float* Wih   = (const float*)d_in[10];
  const float* Whh   = (const float*)d_in[11];
  const float* bih   = (const float*)d_in[12];
  const float* bhh   = (const float*)d_in[13];
  const float* wij_w = (const float*)d_in[14];
  const float* wij_b = (const float*)d_in[15];
  const float* s_i   = (const float*)d_in[16];
  const float* m_i   = (const float*)d_in[17];
  float* out = (float*)d_out;
  char* ws = (char*)d_ws;

  float* phi  = (float*)(ws + OFF_PHI);
  float* wa   = (float*)(ws + OFF_WA);
  float* hpre = (float*)(ws + OFF_HPRE);
  float* ep   = (float*)(ws + OFF_EP);
  float* epsum= (float*)(ws + OFF_EP) + 1000;
  float* ET   = (float*)(ws + OFF_ET);
  unsigned short* X  = (unsigned short*)(ws + OFF_ET);   // aliases ET (dead after k_smx)
  unsigned short* P  = (unsigned short*)(ws + OFF_P);
  unsigned short* LT = (unsigned short*)(ws + OFF_LT);
  unsigned short* Wr = (unsigned short*)(ws + OFF_WR);
  float* phiT        = (float*)(ws + OFF_PT);            // aliases P region (pre-smx)
  float* sums        = (float*)(ws + OFF_SUM);           // aliases P region
  float* WhhT        = (float*)(ws + OFF_WT);            // aliases P region (pre-smx)
  float* WaT         = (float*)(ws + OFF_WAT);           // aliases P region (pre-smx)

  k_tr      <<<dim3(8,8),      dim3(256),  0, stream>>>(phi_w, phiT, 512, 512);
  k_tr      <<<dim3(32,8),     dim3(256),  0, stream>>>(Whh, WhhT, 2048, 512);
  k_tr      <<<dim3(2,8),      dim3(256),  0, stream>>>(Wa_w, WaT, 128, 512);
  k_phiA    <<<dim3(2,8),      dim3(256),  0, stream>>>(phiT, phi, sums);
  k_phiB    <<<dim3(2,8),      dim3(256),  0, stream>>>(sums, phi_b, phi);
  k_wa2     <<<dim3(32),       dim3(256),  0, stream>>>(s_i, WaT, Wa_b, va_w, wa);
  k_hpre2   <<<dim3(2,128),    dim3(256),  0, stream>>>(s_i, WhhT, bih, bhh, hpre);
  k_ep      <<<dim3(224),      dim3(256),  0, stream>>>(CNNs, wij_w, wij_b, s_i, ep);
  k_epsum   <<<dim3(1),        dim3(1024), 0, stream>>>(ep, epsum);
  k_cvtW    <<<dim3(640),      dim3(256),  0, stream>>>(Wih, Wr);
  k_ltrans  <<<dim3(8,8,128),  dim3(256),  0, stream>>>(LSTM, LT);
  k_bandmm  <<<dim3(8,128),    dim3(256),  0, stream>>>(LSTM, phi, Ua_w, Ua_b, va_w, va_b, wa, ET);
  k_smx     <<<dim3(2,128),    dim3(512),  0, stream>>>(ET, P);
  k_cp      <<<dim3(128),      dim3(128),  0, stream>>>(ep, epsum, CNNs, X);
  k_ci_mm   <<<dim3(128,4),    dim3(256),  0, stream>>>(P, LT, X);
  k_gates8  <<<dim3(8,64),     dim3(512),  0, stream>>>(Wr, X, hpre, m_i, out);
}

// Round 7
// 485.490 us; speedup vs baseline: 1.3400x; 1.0073x over previous
//
#include <hip/hip_runtime.h>
#include <hip/hip_bf16.h>

#define B_   128
#define TE_  512
#define TD_  128
#define EH_  512
#define DH_  512
#define KC_  7
#define CC_  105
#define G_   2048   // 4*DH
#define KX_  617    // EH + CC
#define KP_  640    // padded K for gates GEMM
#define GNT  10     // KP_/64 K-tiles for gates GEMM

typedef __attribute__((ext_vector_type(8))) short bf16x8;
typedef __attribute__((ext_vector_type(4))) float f32x4;

__device__ __forceinline__ float sigm(float x){ return 1.f/(1.f + __expf(-x)); }
__device__ __forceinline__ float tanhf_fast(float x){
  float e = __expf(2.f*x);
  return 1.f - 2.f/(e + 1.f);
}

// fp32 -> bf16 (RNE)
__device__ __forceinline__ unsigned short f2bf(float f){
  unsigned int u = __float_as_uint(f);
  unsigned int r = (u + 0x7fffu + ((u >> 16) & 1u)) >> 16;
  return (unsigned short)r;
}

// async global->LDS, 16B per lane; LDS dest = wave-uniform base + lane*16
typedef __attribute__((address_space(3))) unsigned int lds_u32_t;
typedef __attribute__((address_space(1))) const unsigned int glb_u32_t;
__device__ __forceinline__ void gload16(const void* g, void* l) {
  __builtin_amdgcn_global_load_lds((glb_u32_t*)g, (lds_u32_t*)l, 16, 0, 0);
}

// ---------------- workspace layout (bytes) ----------------
static const size_t OFF_PHI  = 0;                                         // 1 MB
static const size_t OFF_WA   = OFF_PHI  + (size_t)TE_*EH_*4;              // 64 KB
static const size_t OFF_HPRE = OFF_WA   + (size_t)B_*TD_*4;               // 1 MB
static const size_t OFF_EP   = OFF_HPRE + (size_t)B_*G_*4;                // 4 KB (ep 896 f + epsum @1000)
static const size_t OFF_CP   = OFF_EP   + 4096;                           // spare
static const size_t OFF_ET   = ((OFF_CP + (size_t)B_*CC_*4 + 255)/256)*256; // X bf16 region (ET retired)
static const size_t OFF_STAT = OFF_ET + (size_t)B_*TE_*TD_*4;             // 128 KB (sinv uses 64 KB)
static const size_t OFF_P    = ((OFF_STAT + (size_t)2*B_*TD_*4 + 255)/256)*256; // 16.7 MB bf16
static const size_t OFF_LT   = OFF_P  + (size_t)B_*TD_*TE_*2;             // 67 MB bf16
static const size_t OFF_WR   = OFF_LT + (size_t)B_*TE_*EH_*2;             // 2.6 MB bf16
static const size_t OFF_SP   = OFF_WR + (size_t)G_*KP_*2;                 // 512 KB fp32 partial sums
// scratch aliases inside P region (all consumed before k_bandmm writes P):
static const size_t OFF_PT   = OFF_P;                                     // 1 MB fp32 phi_w^T
static const size_t OFF_SUM  = OFF_PT + (size_t)TE_*EH_*4;                // 16 KB scan sums
static const size_t OFF_WT   = OFF_P + (size_t)2*1024*1024;               // 4 MB Whh^T fp32
static const size_t OFF_WAT  = OFF_P + (size_t)6*1024*1024;               // 256 KB Wa_w^T fp32

// ---- generic fp32 transpose: src[R][C] -> dst[C][R], 64x64 tiles ----
__global__ __launch_bounds__(256) void k_tr(const float* __restrict__ src,
                                            float* __restrict__ dst, int R, int C) {
  int r0 = blockIdx.x * 64, c0 = blockIdx.y * 64;
  __shared__ float tile[64][65];
  int tid = threadIdx.x;
  int r = tid >> 2, c16 = (tid & 3) * 16;
  const float4* s4 = (const float4*)(src + (size_t)(r0 + r)*C + c0 + c16);
  float4 v0 = s4[0], v1 = s4[1], v2 = s4[2], v3 = s4[3];
  *(float4*)&tile[r][c16]    = v0;
  *(float4*)&tile[r][c16+4]  = v1;
  *(float4*)&tile[r][c16+8]  = v2;
  *(float4*)&tile[r][c16+12] = v3;
  __syncthreads();
  float o[16];
  #pragma unroll
  for (int j = 0; j < 16; ++j) o[j] = tile[c16+j][r];
  float* d = dst + (size_t)(c0 + r)*R + r0 + c16;
  *(float4*)d      = *(float4*)&o[0];
  *(float4*)(d+4)  = *(float4*)&o[4];
  *(float4*)(d+8)  = *(float4*)&o[8];
  *(float4*)(d+12) = *(float4*)&o[12];
}

// ---- split exclusive scan over t ----
__global__ void k_phiA(const float* __restrict__ phiT, float* __restrict__ phi,
                       float* __restrict__ sums) {
  int e = blockIdx.x * 256 + threadIdx.x;   // 512
  int z = blockIdx.y;                        // 8 chunks of 64 t
  float acc = 0.f;
  for (int t = z*64; t < z*64 + 64; ++t) {
    phi[(size_t)t*EH_ + e] = acc;
    acc += phiT[(size_t)t*EH_ + e];
  }
  sums[z*EH_ + e] = acc;
}
__global__ void k_phiB(const float* __restrict__ sums, const float* __restrict__ phi_b,
                       float* __restrict__ phi) {
  int e = blockIdx.x * 256 + threadIdx.x;
  int z = blockIdx.y;
  float off = phi_b[e];
  for (int zz = 0; zz < z; ++zz) off += sums[zz*EH_ + e];
  for (int t = z*64; t < z*64 + 64; ++t)
    phi[(size_t)t*EH_ + e] += off;
}

// ---- wa[b][d] = tanh(s_i[b].Wa_w[d] + Wa_b[d]) * va_w[d], coalesced via WaT ----
__global__ __launch_bounds__(256) void k_wa2(const float* __restrict__ s_i,
                                             const float* __restrict__ WaT,
                                             const float* __restrict__ Wa_b,
                                             const float* __restrict__ va_w,
                                             float* __restrict__ wa) {
  int lane = threadIdx.x & 63, wv = threadIdx.x >> 6;
  int b = blockIdx.x * 4 + wv;               // 32 blocks x 4 waves = 128 b
  int d0 = lane * 2;
  const float2* w = (const float2*)WaT + lane;   // row stride 64 float2
  const float* s = s_i + (size_t)b*DH_;
  float ax = 0.f, ay = 0.f;
  #pragma unroll 8
  for (int k = 0; k < DH_; ++k) {
    float2 wv2 = w[(size_t)k*64];
    float x = s[k];
    ax += wv2.x * x; ay += wv2.y * x;
  }
  wa[b*TD_ + d0]     = tanhf_fast(ax + Wa_b[d0])     * va_w[d0];
  wa[b*TD_ + d0 + 1] = tanhf_fast(ay + Wa_b[d0 + 1]) * va_w[d0 + 1];
}

// ---- hpre[b][g] = bih[g]+bhh[g] + s_i[b].Whh[g], via WhhT ----
__global__ __launch_bounds__(256) void k_hpre2(const float* __restrict__ s_i,
                                               const float* __restrict__ WhhT,
                                               const float* __restrict__ bih,
                                               const float* __restrict__ bhh,
                                               float* __restrict__ hpre) {
  int gq = blockIdx.x * 256 + threadIdx.x;   // 0..511 float4-group of g
  int b  = blockIdx.y;                       // 128
  const float4* w = (const float4*)WhhT + gq;    // row stride 512 float4
  const float* s = s_i + (size_t)b*DH_;
  float4 a = {0.f,0.f,0.f,0.f};
  #pragma unroll 8
  for (int k = 0; k < DH_; ++k) {
    float4 wv = w[(size_t)k*512];
    float x = s[k];
    a.x += wv.x*x; a.y += wv.y*x; a.z += wv.z*x; a.w += wv.w*x;
  }
  int g = gq * 4;
  float4 bi = *(const float4*)(bih + g);
  float4 bh = *(const float4*)(bhh + g);
  float4 o;
  o.x = a.x + bi.x + bh.x; o.y = a.y + bi.y + bh.y;
  o.z = a.z + bi.z + bh.z; o.w = a.w + bi.w + bh.w;
  *(float4*)(hpre + (size_t)b*G_ + g) = o;
}

// ---- ep: one wave per (b,k) ----
__global__ __launch_bounds__(256) void k_ep(const float* __restrict__ CNNs,
                                            const float* __restrict__ wij_w,
                                            const float* __restrict__ wij_b,
                                            const float* __restrict__ s_i,
                                            float* __restrict__ ep) {
  int gw = blockIdx.x * 4 + (threadIdx.x >> 6);
  int lane = threadIdx.x & 63;
  if (gw >= B_*KC_) return;
  int b = gw / KC_, k = gw % KC_;
  const float* cr = CNNs + (size_t)(b*KC_ + k)*CC_;
  const float* wr = wij_w + (size_t)k*KX_;
  float acc = 0.f;
  for (int c = lane; c < CC_; c += 64) acc += cr[c] * wr[c];
  const float* sr = s_i + (size_t)b*DH_;
  const float* wsr = wr + CC_;
  #pragma unroll
  for (int j = 0; j < 8; ++j) { int h = lane + j*64; acc += sr[h] * wsr[h]; }
  #pragma unroll
  for (int m = 32; m; m >>= 1) acc += __shfl_xor(acc, m, 64);
  if (lane == 0) ep[gw] = tanhf_fast(acc + wij_b[k]);
}

// ---- global raw-sum of ep (ref: sum(ep), not sum(exp)) ----
__global__ void k_epsum(const float* __restrict__ ep, float* __restrict__ epsum) {
  __shared__ float red[1024];
  int tid = threadIdx.x;
  red[tid] = (tid < B_*KC_) ? ep[tid] : 0.f;
  __syncthreads();
  for (int off = 512; off > 0; off >>= 1) {
    if (tid < off) red[tid] += red[tid + off];
    __syncthreads();
  }
  if (tid == 0) epsum[0] = red[0];
}

// ---- per-b: ap = exp(ep)/S, c_p = ap.CNNs, write X[:,512:640] bf16 directly ----
__global__ __launch_bounds__(128) void k_cp(const float* __restrict__ ep,
                                            const float* __restrict__ epsum,
                                            const float* __restrict__ CNNs,
                                            unsigned short* __restrict__ X) {
  int b = blockIdx.x, c = threadIdx.x;   // 128 threads
  float S = epsum[0];
  float apl[KC_];
  #pragma unroll
  for (int k = 0; k < KC_; ++k) apl[k] = __expf(ep[b*KC_ + k]) / S;
  float acc = 0.f;
  if (c < CC_) {
    #pragma unroll
    for (int k = 0; k < KC_; ++k)
      acc += apl[k] * CNNs[(size_t)(b*KC_ + k)*CC_ + c];
  }
  unsigned short o = (c < CC_) ? f2bf(acc) : 0;
  unsigned short* xb = X + (size_t)b*TD_*KP_ + EH_ + c;
  for (int i = 0; i < TD_; ++i)
    xb[(size_t)i*KP_] = o;
}

// ---- Wih fp32 -> bf16 [2048][640], rows reordered nr = dh*4+gate ----
__global__ void k_cvtW(const float* __restrict__ Wih, unsigned short* __restrict__ Wr) {
  int id = blockIdx.x * 256 + threadIdx.x;    // 2048*80
  int nr = id / 80, c8 = (id % 80) * 8;
  int gate = nr & 3, dh = nr >> 2;
  const float* src = Wih + (size_t)(gate*DH_ + dh)*KX_;
  unsigned short o[8];
  #pragma unroll
  for (int j = 0; j < 8; ++j) {
    int col = c8 + j;
    o[j] = (col < KX_) ? f2bf(src[col]) : 0;
  }
  *(uint4*)(Wr + (size_t)nr*KP_ + c8) = *(uint4*)o;
}

// ---- LSTM [b][t][e] fp32 -> LT [b][e][t] bf16 ----
__global__ __launch_bounds__(256) void k_ltrans(const float* __restrict__ LSTM,
                                                unsigned short* __restrict__ LT) {
  int e0 = blockIdx.x * 64, t0 = blockIdx.y * 64, b = blockIdx.z;
  __shared__ float tile[64][65];
  int tid = threadIdx.x;
  int tt = tid >> 2, c16 = (tid & 3) * 16;
  const float4* src = (const float4*)(LSTM + ((size_t)b*TE_ + t0 + tt)*EH_ + e0 + c16);
  float4 v0 = src[0], v1 = src[1], v2 = src[2], v3 = src[3];
  *(float4*)&tile[tt][c16]    = v0;
  *(float4*)&tile[tt][c16+4]  = v1;
  *(float4*)&tile[tt][c16+8]  = v2;
  *(float4*)&tile[tt][c16+12] = v3;
  __syncthreads();
  int e = tid >> 2, t16 = (tid & 3) * 16;
  unsigned short o[16];
  #pragma unroll
  for (int j = 0; j < 16; ++j) o[j] = f2bf(tile[t16+j][e]);
  unsigned short* dst = LT + ((size_t)b*EH_ + e0 + e)*TE_ + t0 + t16;
  *(uint4*)dst     = *(uint4*)&o[0];
  *(uint4*)(dst+8) = *(uint4*)&o[8];
}

// ---------- phase 1: banded logits band-GEMM, fused softmax-exp ----------
// Logits are bounded (|tanh|<=1 times small va_w) so max-subtraction is
// unnecessary: emit P = bf16(exp(val)) directly (transposed, unnormalized)
// plus fp32 partial sums per (b, i, t-tile). k_sinv reduces the 8 partials;
// k_ci_mm applies 1/sum per output row. Removes the 33.5MB ET round-trip
// and the whole k_smx pass.
#define BMM_M 64
#define LDA_  40
#define LDB_  40
#define OTS_  132   // tile row stride in floats
__global__ __launch_bounds__(256) void k_bandmm(const float* __restrict__ LSTM,
                                                const float* __restrict__ phi,
                                                const float* __restrict__ Ua_w,
                                                const float* __restrict__ Ua_b,
                                                const float* __restrict__ va_w,
                                                const float* __restrict__ va_b,
                                                const float* __restrict__ wa,
                                                unsigned short* __restrict__ P,
                                                float* __restrict__ sums_p) {
  int t0 = blockIdx.x * BMM_M;   // 8 tiles
  int b  = blockIdx.y;           // 128
  int s_base = 321 - t0;
  __shared__ __align__(16) char smem[BMM_M * OTS_ * 4];   // 33.8 KB
  short* sA = (short*)smem;                 // [64][40]
  short* sB = (short*)(smem + BMM_M*LDA_*2);// [192][40]
  int tid = threadIdx.x;
  int wave = tid >> 6, lane = tid & 63;
  int quad = lane >> 4, l16 = lane & 15;

  f32x4 acc[4][3];
  #pragma unroll
  for (int m = 0; m < 4; ++m)
    #pragma unroll
    for (int n = 0; n < 3; ++n)
      acc[m][n] = (f32x4){0.f, 0.f, 0.f, 0.f};

  int arow = tid >> 2;             // 0..63
  int ach  = (tid & 3) * 8;        // shorts
  int aq   = ach >> 2;             // float4 units

  const float4* baseL = (const float4*)(LSTM + ((size_t)b*TE_ + t0 + arow)*EH_);
  const float4* baseP = (const float4*)(phi + (size_t)(t0 + arow)*EH_);
  const float4* baseU[3];
  int brow[3], bch[3];
  #pragma unroll
  for (int c = 0; c < 3; ++c) {
    int idx = c*256 + tid;
    brow[c] = idx >> 2;
    bch[c]  = (idx & 3) * 8;
    int s = s_base + brow[c];
    int sc = s < 0 ? 0 : (s > 511 ? 511 : s);
    baseU[c] = (const float4*)(Ua_w + (size_t)sc*EH_ + bch[c]);
  }

  float4 l0 = baseL[aq], l1 = baseL[aq+1], p0 = baseP[aq], p1 = baseP[aq+1];
  float4 u0[3], u1[3];
  #pragma unroll
  for (int c = 0; c < 3; ++c) { u0[c] = baseU[c][0]; u1[c] = baseU[c][1]; }

  for (int k0 = 0; k0 < EH_; k0 += 32) {
    unsigned short at[8];
    at[0]=f2bf(l0.x*p0.x); at[1]=f2bf(l0.y*p0.y); at[2]=f2bf(l0.z*p0.z); at[3]=f2bf(l0.w*p0.w);
    at[4]=f2bf(l1.x*p1.x); at[5]=f2bf(l1.y*p1.y); at[6]=f2bf(l1.z*p1.z); at[7]=f2bf(l1.w*p1.w);
    unsigned short bt[3][8];
    #pragma unroll
    for (int c = 0; c < 3; ++c) {
      bt[c][0]=f2bf(u0[c].x); bt[c][1]=f2bf(u0[c].y); bt[c][2]=f2bf(u0[c].z); bt[c][3]=f2bf(u0[c].w);
      bt[c][4]=f2bf(u1[c].x); bt[c][5]=f2bf(u1[c].y); bt[c][6]=f2bf(u1[c].z); bt[c][7]=f2bf(u1[c].w);
    }
    if (k0 + 32 < EH_) {                       // prefetch next chunk
      int q = (k0 + 32) >> 2;
      l0 = baseL[q+aq]; l1 = baseL[q+aq+1]; p0 = baseP[q+aq]; p1 = baseP[q+aq+1];
      #pragma unroll
      for (int c = 0; c < 3; ++c) { u0[c] = baseU[c][q]; u1[c] = baseU[c][q+1]; }
    }
    __syncthreads();
    *(uint4*)&sA[arow*LDA_ + ach] = *(uint4*)at;
    #pragma unroll
    for (int c = 0; c < 3; ++c)
      *(uint4*)&sB[brow[c]*LDB_ + bch[c]] = *(uint4*)bt[c];
    __syncthreads();
    bf16x8 bfr[3];
    #pragma unroll
    for (int n = 0; n < 3; ++n)
      bfr[n] = *(const bf16x8*)&sB[(l16 + (wave*3 + n)*16)*LDB_ + quad*8];
    #pragma unroll
    for (int m = 0; m < 4; ++m) {
      bf16x8 af = *(const bf16x8*)&sA[(l16 + m*16)*LDA_ + quad*8];
      #pragma unroll
      for (int n = 0; n < 3; ++n)
        acc[m][n] = __builtin_amdgcn_mfma_f32_16x16x32_bf16(af, bfr[n], acc[m][n], 0, 0, 0);
    }
  }

  __syncthreads();                 // sA/sB dead -> reuse smem as exp tile
  float* tileO = (float*)smem;     // [64][OTS_]
  float vb = va_b[0];
  #pragma unroll
  for (int n = 0; n < 3; ++n) {
    int s = s_base + wave*48 + n*16 + l16;
    float ub = (s >= 0 && s < TE_) ? Ua_b[s] : 0.f;
    float vw = (s >= 0 && s < TE_) ? va_w[TD_ + s] : 0.f;
    #pragma unroll
    for (int m = 0; m < 4; ++m) {
      #pragma unroll
      for (int r = 0; r < 4; ++r) {
        int tl = m*16 + quad*4 + r;        // t - t0
        int i = s + t0 + tl - 384;
        if (i >= 0 && i < TD_) {
          float val;
          if (s >= 0) val = tanhf_fast(acc[m][n][r] + ub) * vw + vb;
          else        val = wa[b*TD_ + s + 128] + vb;
          tileO[tl*OTS_ + i] = __expf(val);
        }
      }
    }
  }
  __syncthreads();
  // fp32 partial sums over this block's 64 t per i (2-way LDS reads: free)
  if (tid < TD_) {
    float ssum = 0.f;
    #pragma unroll 8
    for (int tl = 0; tl < 64; ++tl) ssum += tileO[tl*OTS_ + tid];
    sums_p[((size_t)b*8 + blockIdx.x)*TD_ + tid] = ssum;
  }
  // P[b][i][t0..t0+64) bf16, 2 threads per i-row, 64B aligned stores
  {
    int ii = tid >> 1, hf = tid & 1;
    unsigned short o[32];
    #pragma unroll
    for (int j = 0; j < 32; ++j)
      o[j] = f2bf(tileO[(hf*32 + j)*OTS_ + ii]);
    unsigned short* dst = P + ((size_t)b*TD_ + ii)*TE_ + t0 + hf*32;
    *(uint4*)dst      = *(uint4*)&o[0];
    *(uint4*)(dst+8)  = *(uint4*)&o[8];
    *(uint4*)(dst+16) = *(uint4*)&o[16];
    *(uint4*)(dst+24) = *(uint4*)&o[24];
  }
}

// ---- sinv[b][i] = 1 / sum_z sums_p[b][z][i] ----
__global__ __launch_bounds__(128) void k_sinv(const float* __restrict__ sums_p,
                                              float* __restrict__ sinv) {
  int b = blockIdx.x, i = threadIdx.x;
  float s = 0.f;
  #pragma unroll
  for (int z = 0; z < 8; ++z) s += sums_p[((size_t)b*8 + z)*TD_ + i];
  sinv[b*TD_ + i] = 1.f / s;
}

// ------ phase 3 (MFMA, BK=32): X[b*128+i][e] = sinv[b][i] * sum_t P[b][i][t]*LT[b][e][t] ------
#define CI_LD 40
__global__ __launch_bounds__(256) void k_ci_mm(const unsigned short* __restrict__ P,
                                               const unsigned short* __restrict__ LT,
                                               const float* __restrict__ sinv,
                                               unsigned short* __restrict__ X) {
  int b = blockIdx.x, e0 = blockIdx.y * 128;
  __shared__ short sA[128 * CI_LD];
  __shared__ short sB[128 * CI_LD];
  int tid = threadIdx.x;
  int wave = tid >> 6, lane = tid & 63, quad = lane >> 4, l16 = lane & 15;
  int wm = wave >> 1, wn = wave & 1;
  int row = tid >> 1, ho = (tid & 1) * 16;

  const unsigned short* pa = P + ((size_t)b*TD_ + row)*TE_ + ho;
  const unsigned short* pb = LT + ((size_t)b*EH_ + e0 + row)*TE_ + ho;

  f32x4 acc[4][4];
  #pragma unroll
  for (int m = 0; m < 4; ++m)
    #pragma unroll
    for (int n = 0; n < 4; ++n)
      acc[m][n] = (f32x4){0.f, 0.f, 0.f, 0.f};

  uint4 a0 = *(const uint4*)pa, a1 = *(const uint4*)(pa + 8);
  uint4 b0 = *(const uint4*)pb, b1 = *(const uint4*)(pb + 8);

  for (int k0 = 0; k0 < TE_; k0 += 32) {
    uint4 na0, na1, nb0, nb1;
    if (k0 + 32 < TE_) {
      na0 = *(const uint4*)(pa + k0 + 32); na1 = *(const uint4*)(pa + k0 + 40);
      nb0 = *(const uint4*)(pb + k0 + 32); nb1 = *(const uint4*)(pb + k0 + 40);
    }
    __syncthreads();
    *(uint4*)&sA[row*CI_LD + ho]     = a0;
    *(uint4*)&sA[row*CI_LD + ho + 8] = a1;
    *(uint4*)&sB[row*CI_LD + ho]     = b0;
    *(uint4*)&sB[row*CI_LD + ho + 8] = b1;
    __syncthreads();
    bf16x8 bfr[4];
    #pragma unroll
    for (int n = 0; n < 4; ++n)
      bfr[n] = *(const bf16x8*)&sB[(wn*64 + n*16 + l16)*CI_LD + quad*8];
    #pragma unroll
    for (int m = 0; m < 4; ++m) {
      bf16x8 af = *(const bf16x8*)&sA[(wm*64 + m*16 + l16)*CI_LD + quad*8];
      #pragma unroll
      for (int n = 0; n < 4; ++n)
        acc[m][n] = __builtin_amdgcn_mfma_f32_16x16x32_bf16(af, bfr[n], acc[m][n], 0, 0, 0);
    }
    a0 = na0; a1 = na1; b0 = nb0; b1 = nb1;
  }

  const float* sv = sinv + b*TD_;
  #pragma unroll
  for (int m = 0; m < 4; ++m) {
    int i = wm*64 + m*16 + quad*4;
    float i0 = sv[i], i1 = sv[i+1], i2 = sv[i+2], i3 = sv[i+3];
    #pragma unroll
    for (int n = 0; n < 4; ++n) {
      int e = e0 + wn*64 + n*16 + l16;
      unsigned short* xp = X + ((size_t)b*TD_ + i)*KP_ + e;
      xp[0]              = f2bf(acc[m][n][0] * i0);
      xp[(size_t)KP_]    = f2bf(acc[m][n][1] * i1);
      xp[(size_t)2*KP_]  = f2bf(acc[m][n][2] * i2);
      xp[(size_t)3*KP_]  = f2bf(acc[m][n][3] * i3);
    }
  }
}

// -- phase 4: 256x256x(BK=64) deep-phase gates GEMM + fused LSTM cell --
__global__ __launch_bounds__(512, 2) void k_gates8(const unsigned short* __restrict__ Wr,
                                                   const unsigned short* __restrict__ X,
                                                   const float* __restrict__ hpre,
                                                   const float* __restrict__ m_i,
                                                   float* __restrict__ out) {
  __shared__ short lds[4 * 256 * 64];       // 128 KiB: [buf][A|B][256][64]
  const int g0  = blockIdx.x * 256;
  const int mi0 = blockIdx.y * 256;
  const int tid  = threadIdx.x;
  const int wave = tid >> 6, lane = tid & 63;
  const int l16 = lane & 15, quad = lane >> 4;
  const int wr = wave >> 2, wc = wave & 3;  // 2 x 4 wave grid, per-wave 128g x 64mi

  // staging geometry (fixed per thread)
  const int srow8 = lane >> 3;              // row within the wave's 8-row chunk
  const int sch   = (lane & 7) ^ srow8;     // pre-swizzled source chunk
  const unsigned short* gA = Wr + (size_t)(g0  + wave*8 + srow8) * KP_ + sch*8;
  const unsigned short* gB = X  + (size_t)(mi0 + wave*8 + srow8) * KP_ + sch*8;
  short* lA0 = lds;
  short* lB0 = lds + 16384;
  short* lA1 = lds + 32768;
  short* lB1 = lds + 49152;

  f32x4 acc[8][4];
  #pragma unroll
  for (int m = 0; m < 8; ++m)
    #pragma unroll
    for (int n = 0; n < 4; ++n) acc[m][n] = (f32x4){0.f, 0.f, 0.f, 0.f};

  auto stage = [&](int kt, int bf) {
    short* la = bf ? lA1 : lA0;
    short* lb = bf ? lB1 : lB0;
    const unsigned short* ga = gA + kt*64;
    const unsigned short* gb = gB + kt*64;
    #pragma unroll
    for (int r = 0; r < 4; ++r) {           // rounds: rows r*64 + wave*8 + srow8
      gload16(ga + (size_t)r*64*KP_, la + (r*8 + wave)*512);
      gload16(gb + (size_t)r*64*KP_, lb + (r*8 + wave)*512);
    }
  };

  stage(0, 0);
  __syncthreads();                           // drains vmcnt: tile 0 resident

  const int x7 = l16 & 7;
  for (int kt = 0; kt < GNT; ++kt) {
    const int cur = kt & 1;
    if (kt + 1 < GNT) stage(kt + 1, cur ^ 1);   // prefetch, 4 phases of cover
    const short* la = cur ? lA1 : lA0;
    const short* lb = cur ? lB1 : lB0;
    #pragma unroll
    for (int ks = 0; ks < 2; ++ks) {
      const int ck = ((((ks << 2) | quad) ^ x7) << 3);   // swizzled col (shorts)
      bf16x8 bv[4];
      #pragma unroll
      for (int n = 0; n < 4; ++n)
        bv[n] = *(const bf16x8*)&lb[(wc*64 + n*16 + l16)*64 + ck];
      #pragma unroll
      for (int qm = 0; qm < 2; ++qm) {
        bf16x8 av[4];
        #pragma unroll
        for (int m = 0; m < 4; ++m)
          av[m] = *(const bf16x8*)&la[(wr*128 + qm*64 + m*16 + l16)*64 + ck];
        __builtin_amdgcn_s_setprio(1);
        #pragma unroll
        for (int m = 0; m < 4; ++m)
          #pragma unroll
          for (int n = 0; n < 4; ++n)
            acc[qm*4 + m][n] = __builtin_amdgcn_mfma_f32_16x16x32_bf16(av[m], bv[n], acc[qm*4 + m][n], 0, 0, 0);
        __builtin_amdgcn_s_setprio(0);
      }
    }
    __syncthreads();   // implicit vmcnt(0): tile kt+1 landed; frees buf cur
  }

  // epilogue: lane regs r=0..3 are (ig,fg,gg,og) of one dh; b uniform per wave
  const int bb = (mi0 >> 7) + (wc >> 1);
  const float* hp = hpre + (size_t)bb * G_;
  #pragma unroll
  for (int M = 0; M < 8; ++M) {
    const int dh = (g0 >> 2) + wr*32 + M*4 + quad;
    float h0 = hp[dh], h1 = hp[DH_ + dh], h2 = hp[2*DH_ + dh], h3 = hp[3*DH_ + dh];
    float miv = m_i[(size_t)bb*DH_ + dh];
    #pragma unroll
    for (int n = 0; n < 4; ++n) {
      int mi = mi0 + wc*64 + n*16 + l16;
      float ig = acc[M][n][0] + h0;
      float fg = acc[M][n][1] + h1;
      float gg = acc[M][n][2] + h2;
      float og = acc[M][n][3] + h3;
      float c  = sigm(fg)*miv + sigm(ig)*tanhf_fast(gg);
      float h  = sigm(og)*tanhf_fast(c);
      out[(size_t)mi*DH_ + dh] = h;
    }
  }
}

extern "C" void kernel_launch(void* const* d_in, const int* in_sizes, int n_in,
                              void* d_out, int out_size, void* d_ws, size_t ws_size,
                              hipStream_t stream) {
  (void)in_sizes; (void)n_in; (void)out_size; (void)ws_size;
  const float* LSTM  = (const float*)d_in[0];
  const float* CNNs  = (const float*)d_in[1];
  const float* Wa_w  = (const float*)d_in[2];
  const float* Wa_b  = (const float*)d_in[3];
  const float* Ua_w  = (const float*)d_in[4];
  const float* Ua_b  = (const float*)d_in[5];
  const float* va_w  = (const float*)d_in[6];
  const float* va_b  = (const float*)d_in[7];
  const float* phi_w = (const float*)d_in[8];
  const float* phi_b = (const float*)d_in[9];
  const float* Wih   = (const float*)d_in[10];
  const float* Whh   = (const float*)d_in[11];
  const float* bih   = (const float*)d_in[12];
  const float* bhh   = (const float*)d_in[13];
  const float* wij_w = (const float*)d_in[14];
  const float* wij_b = (const float*)d_in[15];
  const float* s_i   = (const float*)d_in[16];
  const float* m_i   = (const float*)d_in[17];
  float* out = (float*)d_out;
  char* ws = (char*)d_ws;

  float* phi  = (float*)(ws + OFF_PHI);
  float* wa   = (float*)(ws + OFF_WA);
  float* hpre = (float*)(ws + OFF_HPRE);
  float* ep   = (float*)(ws + OFF_EP);
  float* epsum= (float*)(ws + OFF_EP) + 1000;
  unsigned short* X  = (unsigned short*)(ws + OFF_ET);
  float* sinv        = (float*)(ws + OFF_STAT);
  unsigned short* P  = (unsigned short*)(ws + OFF_P);
  unsigned short* LT = (unsigned short*)(ws + OFF_LT);
  unsigned short* Wr = (unsigned short*)(ws + OFF_WR);
  float* sums_p      = (float*)(ws + OFF_SP);
  float* phiT        = (float*)(ws + OFF_PT);            // aliases P region (pre-bandmm)
  float* sums        = (float*)(ws + OFF_SUM);           // aliases P region
  float* WhhT        = (float*)(ws + OFF_WT);            // aliases P region (pre-bandmm)
  float* WaT         = (float*)(ws + OFF_WAT);           // aliases P region (pre-bandmm)

  k_tr      <<<dim3(8,8),      dim3(256),  0, stream>>>(phi_w, phiT, 512, 512);
  k_tr      <<<dim3(32,8),     dim3(256),  0, stream>>>(Whh, WhhT, 2048, 512);
  k_tr      <<<dim3(2,8),      dim3(256),  0, stream>>>(Wa_w, WaT, 128, 512);
  k_phiA    <<<dim3(2,8),      dim3(256),  0, stream>>>(phiT, phi, sums);
  k_phiB    <<<dim3(2,8),      dim3(256),  0, stream>>>(sums, phi_b, phi);
  k_wa2     <<<dim3(32),       dim3(256),  0, stream>>>(s_i, WaT, Wa_b, va_w, wa);
  k_hpre2   <<<dim3(2,128),    dim3(256),  0, stream>>>(s_i, WhhT, bih, bhh, hpre);
  k_ep      <<<dim3(224),      dim3(256),  0, stream>>>(CNNs, wij_w, wij_b, s_i, ep);
  k_epsum   <<<dim3(1),        dim3(1024), 0, stream>>>(ep, epsum);
  k_cvtW    <<<dim3(640),      dim3(256),  0, stream>>>(Wih, Wr);
  k_ltrans  <<<dim3(8,8,128),  dim3(256),  0, stream>>>(LSTM, LT);
  k_bandmm  <<<dim3(8,128),    dim3(256),  0, stream>>>(LSTM, phi, Ua_w, Ua_b, va_w, va_b, wa, P, sums_p);
  k_sinv    <<<dim3(128),      dim3(128),  0, stream>>>(sums_p, sinv);
  k_cp      <<<dim3(128),      dim3(128),  0, stream>>>(ep, epsum, CNNs, X);
  k_ci_mm   <<<dim3(128,4),    dim3(256),  0, stream>>>(P, LT, sinv, X);
  k_gates8  <<<dim3(8,64),     dim3(512),  0, stream>>>(Wr, X, hpre, m_i, out);
}